// Round 1
// 307.520 us; speedup vs baseline: 1.0534x; 1.0534x over previous
//
#include <hip/hip_runtime.h>

#define B_ 8
#define C_ 256
#define N_ 4096
#define G_ 32

typedef __bf16 bf16;
typedef __bf16 bf16x8 __attribute__((ext_vector_type(8)));
typedef float f32x4 __attribute__((ext_vector_type(4)));
typedef long i64;
typedef long i64x2 __attribute__((ext_vector_type(2)));
typedef unsigned int u32;
typedef unsigned char u8;
typedef unsigned short u16;
// may_alias types for the P LDS round-trip: the u16 stores and i64 loads hit
// the same bytes; without this TBAA lets the compiler hoist the ds_read above
// the ds_write (R7's NaN: stale LDS bytes -> fp8 NaN encodings -> MFMA NaN).
typedef unsigned short __attribute__((may_alias)) u16a;
typedef long __attribute__((may_alias)) i64a;

__device__ __forceinline__ f32x4 mfma16(bf16x8 a, bf16x8 b, f32x4 c) {
    return __builtin_amdgcn_mfma_f32_16x16x32_bf16(a, b, c, 0, 0, 0);
}
__device__ __forceinline__ f32x4 mfma_fp8(i64 a, i64 b, f32x4 c) {
    return __builtin_amdgcn_mfma_f32_16x16x32_fp8_fp8(a, b, c, 0, 0, 0);
}

typedef __attribute__((address_space(1))) const void* gas_t;
typedef __attribute__((address_space(3))) void* las_t;
__device__ __forceinline__ void gl2lds16(const void* g, void* l) {
    __builtin_amdgcn_global_load_lds((gas_t)g, (las_t)l, 16, 0, 0);
}

// Full-range f32 -> OCP e4m3fn (NaN-free by construction).
__device__ __forceinline__ u32 f32_to_fp8(float x) {
    union { float f; u32 u; } c;
    c.f = x;
    u32 s = (c.u >> 24) & 0x80;
    u32 m = (c.u & 0x7fffffff) + 0x00080000;
    int e = (int)(m >> 23) - 127;
    if (e < -6) return s;
    if (e > 8) return s | 0x7e;
    u32 v = ((u32)(e + 7) << 3) | ((m >> 20) & 7);
    if (v > 0x7e) v = 0x7e;
    return s | v;
}
// 3-op converter for known-positive x in [2^-6, 2^8): exp() outputs only.
__device__ __forceinline__ u32 fp8_fast(float x) {
    union { float f; u32 u; } c;
    c.f = x;
    return ((c.u + 0x00080000u) >> 20) - 960u;  // low 8 bits valid
}

// ---------------------------------------------------------------------------
// Kernel 1: GroupNorm statistics. One block per (batch, group).
// ---------------------------------------------------------------------------
__global__ __launch_bounds__(256) void gn_stats(const float* __restrict__ x,
                                                float* __restrict__ gstats) {
    int blk = blockIdx.x;  // b*32 + g
    int b = blk >> 5, g = blk & 31;
    int tid = threadIdx.x;
    int c = g * 8 + (tid >> 5);
    const float* row = x + ((size_t)(b * C_ + c)) * N_;
    float s = 0.f, s2 = 0.f;
    for (int n = (tid & 31) * 4; n < N_; n += 128) {
        float4 v = *(const float4*)(row + n);
        s += v.x + v.y + v.z + v.w;
        s2 += v.x * v.x + v.y * v.y + v.z * v.z + v.w * v.w;
    }
    for (int off = 32; off; off >>= 1) {
        s += __shfl_xor(s, off);
        s2 += __shfl_xor(s2, off);
    }
    __shared__ float red[8];
    int wid = tid >> 6;
    if ((tid & 63) == 0) { red[wid] = s; red[4 + wid] = s2; }
    __syncthreads();
    if (tid == 0) {
        float S = red[0] + red[1] + red[2] + red[3];
        float S2 = red[4] + red[5] + red[6] + red[7];
        float mean = S * (1.f / 32768.f);
        float var = S2 * (1.f / 32768.f) - mean * mean;
        gstats[blk * 2] = mean;
        gstats[blk * 2 + 1] = rsqrtf(var + 1e-6f);
    }
}

// ---------------------------------------------------------------------------
// Kernel 2: apply GroupNorm + transpose [b][c][n] fp32 -> [b*n][c] bf16.
// ---------------------------------------------------------------------------
__global__ __launch_bounds__(256) void gn_apply(const float* __restrict__ x,
                                                const float* __restrict__ gsc,
                                                const float* __restrict__ gbi,
                                                const float* __restrict__ gstats,
                                                bf16* __restrict__ hn) {
    __shared__ float tile[32][33];
    int b = blockIdx.z, c0 = blockIdx.y * 32, n0 = blockIdx.x * 32;
    int tx = threadIdx.x & 31, ty = threadIdx.x >> 5;
    for (int i = 0; i < 4; i++) {
        int cl = ty + i * 8;
        int c = c0 + cl;
        int g = c >> 3;
        float mean = gstats[(b * G_ + g) * 2];
        float rstd = gstats[(b * G_ + g) * 2 + 1];
        float sc = gsc[c] * rstd;
        float bs = gbi[c] - mean * sc;
        float v = x[((size_t)(b * C_ + c)) * N_ + n0 + tx];
        tile[cl][tx] = v * sc + bs;
    }
    __syncthreads();
    for (int i = 0; i < 4; i++) {
        int nl = ty + i * 8;
        hn[((size_t)(b * N_ + n0 + nl)) * C_ + c0 + tx] = (bf16)tile[tx][nl];
    }
}

// ---------------------------------------------------------------------------
// Kernel 3: convert the four 256x256 fp32 weight matrices to bf16 once.
// ---------------------------------------------------------------------------
__global__ __launch_bounds__(256) void cvt_w(const float* __restrict__ wq,
                                             const float* __restrict__ wk,
                                             const float* __restrict__ wv,
                                             const float* __restrict__ wp,
                                             bf16* __restrict__ dst) {
    int i = blockIdx.x * 256 + threadIdx.x;
    dst[i] = (bf16)wq[i];
    dst[65536 + i] = (bf16)wk[i];
    dst[131072 + i] = (bf16)wv[i];
    dst[196608 + i] = (bf16)wp[i];
}

// ---------------------------------------------------------------------------
// Kernel 4: merged Q+K+V NT GEMM. Stages the A (hn) tile ONCE for all three
// weight matrices (global_load_lds width-16 staging, no VGPR round trip).
// Epilogue writes fp8 directly:
//   q8/k8: token-major, sigma channel permutation baked in via
//          p = sigma^{-1}(col) = (c&0xC0)|((c&0x18)<<1)|((c&0x20)>>2)|(c&7)
//   v8:    channel-major, pi key permutation pos(n)=((n&15)<<1)|((n>>4)&1)
// This replaces gemm_qk + gemm_nt_ch + cvt_qk + cvt_v (saves ~115 MB of
// HBM round trips and one full re-read of hn).
// ---------------------------------------------------------------------------
__global__ __launch_bounds__(256) void gemm_qkv(const bf16* __restrict__ A,
                                                const bf16* __restrict__ Wq,
                                                const bf16* __restrict__ Wk,
                                                const bf16* __restrict__ Wv,
                                                const float* __restrict__ bq,
                                                const float* __restrict__ bk,
                                                const float* __restrict__ bv,
                                                u8* __restrict__ q8,
                                                u8* __restrict__ k8,
                                                u8* __restrict__ v8) {
    __shared__ __align__(16) bf16 As[64][32];
    __shared__ __align__(16) bf16 Wqs[64][32];
    __shared__ __align__(16) bf16 Wks[64][32];
    __shared__ __align__(16) bf16 Wvs[64][32];
    int m0 = blockIdx.x * 64;  // token
    int n0 = blockIdx.y * 64;  // out channel
    int tid = threadIdx.x;
    int wv_ = tid >> 6, lane = tid & 63, lr = lane & 15, lq = lane >> 4;
    int wm = (wv_ & 1) * 32, wn = (wv_ >> 1) * 32;
    int sr = tid >> 2, sk = (tid & 3) * 8;  // LDS byte offset == tid*16 (linear)
    f32x4 qacc[2][2] = {}, kacc[2][2] = {}, vacc[2][2] = {};
    for (int kk = 0; kk < C_; kk += 32) {
        __syncthreads();
        gl2lds16(&A[(size_t)(m0 + sr) * C_ + kk + sk], &As[sr][sk]);
        gl2lds16(&Wq[(size_t)(n0 + sr) * C_ + kk + sk], &Wqs[sr][sk]);
        gl2lds16(&Wk[(size_t)(n0 + sr) * C_ + kk + sk], &Wks[sr][sk]);
        gl2lds16(&Wv[(size_t)(n0 + sr) * C_ + kk + sk], &Wvs[sr][sk]);
        __syncthreads();
        bf16x8 a0 = *(const bf16x8*)&As[wm + lr][lq * 8];
        bf16x8 a1 = *(const bf16x8*)&As[wm + 16 + lr][lq * 8];
        bf16x8 q0 = *(const bf16x8*)&Wqs[wn + lr][lq * 8];
        bf16x8 q1 = *(const bf16x8*)&Wqs[wn + 16 + lr][lq * 8];
        bf16x8 k0 = *(const bf16x8*)&Wks[wn + lr][lq * 8];
        bf16x8 k1 = *(const bf16x8*)&Wks[wn + 16 + lr][lq * 8];
        bf16x8 v0 = *(const bf16x8*)&Wvs[wn + lr][lq * 8];
        bf16x8 v1 = *(const bf16x8*)&Wvs[wn + 16 + lr][lq * 8];
        qacc[0][0] = mfma16(a0, q0, qacc[0][0]);
        qacc[0][1] = mfma16(a0, q1, qacc[0][1]);
        qacc[1][0] = mfma16(a1, q0, qacc[1][0]);
        qacc[1][1] = mfma16(a1, q1, qacc[1][1]);
        kacc[0][0] = mfma16(a0, k0, kacc[0][0]);
        kacc[0][1] = mfma16(a0, k1, kacc[0][1]);
        kacc[1][0] = mfma16(a1, k0, kacc[1][0]);
        kacc[1][1] = mfma16(a1, k1, kacc[1][1]);
        vacc[0][0] = mfma16(a0, v0, vacc[0][0]);
        vacc[0][1] = mfma16(a0, v1, vacc[0][1]);
        vacc[1][0] = mfma16(a1, v0, vacc[1][0]);
        vacc[1][1] = mfma16(a1, v1, vacc[1][1]);
    }
    for (int i = 0; i < 2; i++)
        for (int j = 0; j < 2; j++) {
            int col = n0 + wn + j * 16 + lr;
            // inverse sigma: write channel col to fp8 position p
            int p = (col & 0xC0) | ((col & 0x18) << 1) | ((col & 0x20) >> 2) | (col & 7);
            float bvq = bq[col], bvk = bk[col], bvv = bv[col];
            for (int r = 0; r < 4; r++) {
                int row = m0 + wm + i * 16 + lq * 4 + r;
                q8[(size_t)row * C_ + p] = (u8)f32_to_fp8(qacc[i][j][r] + bvq);
                k8[(size_t)row * C_ + p] = (u8)f32_to_fp8(kacc[i][j][r] + bvk);
                int bb = row >> 12, n = row & (N_ - 1);
                v8[((size_t)(bb * C_ + col)) * N_ + (n & ~31) +
                   (((n & 15) << 1) | ((n >> 4) & 1))] =
                    (u8)f32_to_fp8(vacc[i][j][r] + bvv);
            }
        }
}

// ---------------------------------------------------------------------------
// Kernel 6: fp8 flash attention, fixed-max softmax, block-level split-K.
//   (unchanged from the 322 us session version)
// ---------------------------------------------------------------------------
__global__ __launch_bounds__(128, 2) void attn(const u8* __restrict__ q,
                                               const u8* __restrict__ k,
                                               const u8* __restrict__ vT,
                                               bf16* __restrict__ O0,
                                               bf16* __restrict__ O1,
                                               float* __restrict__ lp) {
    __shared__ __align__(16) u8 smem[35840];
    u8* Ks = smem;           // [2][32*256] fp8 = 16 KB
    u8* Vt = smem + 16384;   // [2][256*32] fp8 = 16 KB
    u8* Ps = smem + 32768;   // [2 waves][32 rows * 48 B] = 3 KB

    int b = blockIdx.z, h = blockIdx.y, q0 = blockIdx.x * 64;
    int tid = threadIdx.x;
    int w = tid >> 6, lane = tid & 63, lr = lane & 15, lq = lane >> 4;

    const u8* kglob = k + ((size_t)(b * N_) + h * 2048) * 256;
    const u8* vglob = vT + (size_t)b * C_ * N_ + h * 2048;

    u32 offK[4], offV[4];
#pragma unroll
    for (int j = 0; j < 4; j++) {
        int p = ((w * 4 + j) << 6) + lane;  // 0..511
        int rK = p >> 4, cK = (p & 15) ^ (rK & 15);
        offK[j] = rK * 256 + cK * 16;
        int rV = p >> 1, cV = (p & 1) ^ ((rV >> 2) & 1);
        offV[j] = rV * N_ + cV * 16;
    }

    // Q fragments (fp8, sigma-permuted): [subtile t][tq] b128 = k-steps 2tq,2tq+1.
    i64x2 qf[2][4];
#pragma unroll
    for (int t = 0; t < 2; t++) {
        const u8* qrow = q + ((size_t)(b * N_ + q0 + w * 32 + t * 16 + lr)) * 256;
#pragma unroll
        for (int tq = 0; tq < 4; tq++)
            qf[t][tq] = *(const i64x2*)&qrow[tq * 64 + lq * 16];
    }

    f32x4 oacc[2][16] = {};
    float li[2][4] = {};
    u8* Pw = Ps + w * 1536;

    // Prologue: stage tile 0 into buffer 0.
#pragma unroll
    for (int j = 0; j < 4; j++) {
        gl2lds16(kglob + offK[j], Ks + ((w * 4 + j) << 10));
        gl2lds16(vglob + offV[j], Vt + ((w * 4 + j) << 10));
    }

    for (int mt = 0; mt < 64; mt++) {
        int cur = mt & 1;
        __syncthreads();

        if (mt < 63) {
            const u8* kit = kglob + (size_t)(mt + 1) * 32 * 256;
            const u8* vit = vglob + (mt + 1) * 32;
#pragma unroll
            for (int j = 0; j < 4; j++) {
                gl2lds16(kit + offK[j], Ks + (cur ^ 1) * 8192 + ((w * 4 + j) << 10));
                gl2lds16(vit + offV[j], Vt + (cur ^ 1) * 8192 + ((w * 4 + j) << 10));
            }
        }

        const u8* Kb = Ks + cur * 8192;
        const u8* Vb = Vt + cur * 8192;

        // --- S = Q K^T: 32 queries x 32 keys ---
        f32x4 st[2][2] = {};
#pragma unroll
        for (int kt = 0; kt < 2; kt++) {
            int r = kt * 16 + lr;
#pragma unroll
            for (int tq = 0; tq < 4; tq++) {
                i64x2 kf = *(const i64x2*)&Kb[r * 256 + (((tq * 4 + lq) ^ (r & 15)) << 4)];
                st[0][kt] = mfma_fp8(qf[0][tq].x, kf.x, st[0][kt]);
                st[0][kt] = mfma_fp8(qf[0][tq].y, kf.y, st[0][kt]);
                st[1][kt] = mfma_fp8(qf[1][tq].x, kf.x, st[1][kt]);
                st[1][kt] = mfma_fp8(qf[1][tq].y, kf.y, st[1][kt]);
            }
        }

        // --- fixed-max softmax numerators -> fp8 P (3-op convert, b16 write)
        //     P key order: pos = 2*lr + kt (matches the pi permutation) ---
#pragma unroll
        for (int t = 0; t < 2; t++)
#pragma unroll
            for (int r = 0; r < 4; r++) {
                float e0 = __expf(st[t][0][r] * 0.0625f);
                float e1 = __expf(st[t][1][r] * 0.0625f);
                li[t][r] += e0 + e1;
                u16 pk = (u16)((fp8_fast(e0) & 0xff) | ((fp8_fast(e1) & 0xff) << 8));
                *(u16a*)&Pw[(t * 16 + lq * 4 + r) * 48 + lr * 2] = pk;
            }

        // Order the P stores before the P loads (compiler fence + lgkmcnt).
        __threadfence_block();

        // --- PV: P (32x32) x V (32x256) ---
        i64 pf[2];
#pragma unroll
        for (int t = 0; t < 2; t++)
            pf[t] = *(const i64a*)&Pw[(t * 16 + lr) * 48 + lq * 8];
#pragma unroll
        for (int ct = 0; ct < 16; ct++) {
            int row = ct * 16 + lr;
            i64 vf = *(const i64a*)&Vb[row * 32 + (((lq >> 1) ^ ((row >> 2) & 1)) << 4) +
                                       ((lq & 1) << 3)];
            oacc[0][ct] = mfma_fp8(pf[0], vf, oacc[0][ct]);
            oacc[1][ct] = mfma_fp8(pf[1], vf, oacc[1][ct]);
        }
    }

    // Reduce per-lane l partials across the 16 lr-lanes.
    float lsum[2][4];
#pragma unroll
    for (int t = 0; t < 2; t++)
#pragma unroll
        for (int r = 0; r < 4; r++) {
            float s = li[t][r];
            s += __shfl_xor(s, 1);
            s += __shfl_xor(s, 2);
            s += __shfl_xor(s, 4);
            s += __shfl_xor(s, 8);
            lsum[t][r] = s;
        }

    bf16* Op = h ? O1 : O0;
#pragma unroll
    for (int t = 0; t < 2; t++)
#pragma unroll
        for (int ct = 0; ct < 16; ct++)
#pragma unroll
            for (int r = 0; r < 4; r++)
                Op[((size_t)(b * N_ + q0 + w * 32 + t * 16 + lq * 4 + r)) * C_ + ct * 16 + lr] =
                    (bf16)oacc[t][ct][r];
    if (lr == 0) {
        float* lrow = lp + ((size_t)(h * B_ + b)) * N_ + q0 + w * 32;
#pragma unroll
        for (int t = 0; t < 2; t++)
#pragma unroll
            for (int r = 0; r < 4; r++) lrow[t * 16 + lq * 4 + r] = lsum[t][r];
    }
}

// ---------------------------------------------------------------------------
// Kernel 7: proj + residual, with the split-K combine fused into A-staging:
//   A_tile = (O0 + O1) * 1/(l0+l1)  (token row is fixed per thread, so the
//   reciprocal is computed once). W staged via global_load_lds.
// Replaces combine + proj_res (saves a 50 MB round trip).
// ---------------------------------------------------------------------------
__global__ __launch_bounds__(256) void proj_res(const bf16* __restrict__ W,
                                                const bf16* __restrict__ O0,
                                                const bf16* __restrict__ O1,
                                                const float* __restrict__ lp,
                                                const float* __restrict__ bias,
                                                const float* __restrict__ x,
                                                float* __restrict__ out) {
    __shared__ __align__(16) bf16 Ws[64][32];
    __shared__ __align__(16) bf16 As[64][32];
    int m0 = blockIdx.x * 64;  // o
    int n0 = blockIdx.y * 64;  // token
    int tid = threadIdx.x;
    int wv_ = tid >> 6, lane = tid & 63, lr = lane & 15, lq = lane >> 4;
    int wm = (wv_ & 1) * 32, wn = (wv_ >> 1) * 32;
    int sr = tid >> 2, sk = (tid & 3) * 8;
    int T = n0 + sr, bb = T >> 12, nn = T & (N_ - 1);
    float inv = 1.f / (lp[(size_t)bb * N_ + nn] + lp[(size_t)(B_ + bb) * N_ + nn]);
    f32x4 acc[2][2] = {};
    for (int kk = 0; kk < C_; kk += 32) {
        __syncthreads();
        gl2lds16(&W[(size_t)(m0 + sr) * C_ + kk + sk], &Ws[sr][sk]);
        bf16x8 o0 = *(const bf16x8*)&O0[(size_t)T * C_ + kk + sk];
        bf16x8 o1 = *(const bf16x8*)&O1[(size_t)T * C_ + kk + sk];
        bf16x8 cm;
#pragma unroll
        for (int e = 0; e < 8; e++) cm[e] = (bf16)(((float)o0[e] + (float)o1[e]) * inv);
        *(bf16x8*)&As[sr][sk] = cm;
        __syncthreads();
        bf16x8 a0 = *(const bf16x8*)&Ws[wm + lr][lq * 8];
        bf16x8 a1 = *(const bf16x8*)&Ws[wm + 16 + lr][lq * 8];
        bf16x8 b0 = *(const bf16x8*)&As[wn + lr][lq * 8];
        bf16x8 b1 = *(const bf16x8*)&As[wn + 16 + lr][lq * 8];
        acc[0][0] = mfma16(a0, b0, acc[0][0]);
        acc[0][1] = mfma16(a0, b1, acc[0][1]);
        acc[1][0] = mfma16(a1, b0, acc[1][0]);
        acc[1][1] = mfma16(a1, b1, acc[1][1]);
    }
    for (int i = 0; i < 2; i++)
        for (int j = 0; j < 2; j++) {
            int Tt = n0 + wn + j * 16 + lr;
            int b = Tt >> 12, n = Tt & (N_ - 1);
            for (int r = 0; r < 4; r++) {
                int o = m0 + wm + i * 16 + lq * 4 + r;
                size_t idx = ((size_t)(b * C_ + o)) * N_ + n;
                out[idx] = x[idx] + acc[i][j][r] + bias[o];
            }
        }
}

// ---------------------------------------------------------------------------
extern "C" void kernel_launch(void* const* d_in, const int* in_sizes, int n_in,
                              void* d_out, int out_size, void* d_ws, size_t ws_size,
                              hipStream_t stream) {
    const float* x = (const float*)d_in[0];
    const float* gsc = (const float*)d_in[1];
    const float* gbi = (const float*)d_in[2];
    const float* wq = (const float*)d_in[3];
    const float* bq = (const float*)d_in[4];
    const float* wk = (const float*)d_in[5];
    const float* bk = (const float*)d_in[6];
    const float* wv = (const float*)d_in[7];
    const float* bv = (const float*)d_in[8];
    const float* wp = (const float*)d_in[9];
    const float* bp = (const float*)d_in[10];
    float* out = (float*)d_out;

    const size_t SZ = (size_t)B_ * N_ * C_;  // 8388608 elements
    char* ws = (char*)d_ws;
    float* gstats = (float*)ws;              // 4 KB slot
    bf16* wb = (bf16*)(ws + 4096);           // 512 KB
    char* base = ws + 4096 + 524288;
    // Layout (59.5 MB total):
    //   [0,      SZ*2) hn  (bf16)  -> reused as O0 after gemm_qkv
    //   [SZ*2,   SZ*3) q8  (fp8)
    //   [SZ*3,   SZ*4) k8  (fp8)
    //   [SZ*4,   SZ*5) v8  (fp8)
    //   [SZ*5,   SZ*7) O1  (bf16)
    //   [SZ*7,  +256K) lpart (f32)
    bf16* hn = (bf16*)base;
    u8* q8 = (u8*)(base + SZ * 2);
    u8* k8 = (u8*)(base + SZ * 3);
    u8* v8 = (u8*)(base + SZ * 4);
    bf16* O0 = (bf16*)base;                  // hn dead after gemm_qkv
    bf16* O1 = (bf16*)(base + SZ * 5);
    float* lpart = (float*)(base + SZ * 7);

    cvt_w<<<256, 256, 0, stream>>>(wq, wk, wv, wp, wb);
    gn_stats<<<B_ * G_, 256, 0, stream>>>(x, gstats);
    gn_apply<<<dim3(N_ / 32, C_ / 32, B_), 256, 0, stream>>>(x, gsc, gbi, gstats, hn);
    gemm_qkv<<<dim3(B_ * N_ / 64, C_ / 64), 256, 0, stream>>>(
        hn, wb, wb + 65536, wb + 131072, bq, bk, bv, q8, k8, v8);
    attn<<<dim3(N_ / 64, 2, B_), 128, 0, stream>>>(q8, k8, v8, O0, O1, lpart);
    proj_res<<<dim3(C_ / 64, B_ * N_ / 64), 256, 0, stream>>>(
        wb + 196608, O0, O1, lpart, bp, x, out);
}

// Round 2
// 306.602 us; speedup vs baseline: 1.0565x; 1.0030x over previous
//
#include <hip/hip_runtime.h>

#define B_ 8
#define C_ 256
#define N_ 4096
#define G_ 32

typedef __bf16 bf16;
typedef __bf16 bf16x8 __attribute__((ext_vector_type(8)));
typedef float f32x4 __attribute__((ext_vector_type(4)));
typedef long i64;
typedef long i64x2 __attribute__((ext_vector_type(2)));
typedef unsigned int u32;
typedef unsigned char u8;
typedef unsigned short u16;
typedef unsigned long long u64;
// may_alias: LDS V-tile bytes are written by global_load_lds and read as i64.
typedef long __attribute__((may_alias)) i64a;

__device__ __forceinline__ f32x4 mfma16(bf16x8 a, bf16x8 b, f32x4 c) {
    return __builtin_amdgcn_mfma_f32_16x16x32_bf16(a, b, c, 0, 0, 0);
}
__device__ __forceinline__ f32x4 mfma_fp8(i64 a, i64 b, f32x4 c) {
    return __builtin_amdgcn_mfma_f32_16x16x32_fp8_fp8(a, b, c, 0, 0, 0);
}

typedef __attribute__((address_space(1))) const void* gas_t;
typedef __attribute__((address_space(3))) void* las_t;
__device__ __forceinline__ void gl2lds16(const void* g, void* l) {
    __builtin_amdgcn_global_load_lds((gas_t)g, (las_t)l, 16, 0, 0);
}

// Full-range f32 -> OCP e4m3fn (NaN-free by construction).
__device__ __forceinline__ u32 f32_to_fp8(float x) {
    union { float f; u32 u; } c;
    c.f = x;
    u32 s = (c.u >> 24) & 0x80;
    u32 m = (c.u & 0x7fffffff) + 0x00080000;
    int e = (int)(m >> 23) - 127;
    if (e < -6) return s;
    if (e > 8) return s | 0x7e;
    u32 v = ((u32)(e + 7) << 3) | ((m >> 20) & 7);
    if (v > 0x7e) v = 0x7e;
    return s | v;
}
// 3-op converter for known-positive x in [2^-6, 2^8): exp() outputs only.
// Low 8 bits valid; callers mask.
__device__ __forceinline__ u32 fp8_fast(float x) {
    union { float f; u32 u; } c;
    c.f = x;
    return ((c.u + 0x00080000u) >> 20) - 960u;
}

// ---------------------------------------------------------------------------
// Kernel 1: GroupNorm statistics. One block per (batch, group).
// ---------------------------------------------------------------------------
__global__ __launch_bounds__(256) void gn_stats(const float* __restrict__ x,
                                                float* __restrict__ gstats) {
    int blk = blockIdx.x;  // b*32 + g
    int b = blk >> 5, g = blk & 31;
    int tid = threadIdx.x;
    int c = g * 8 + (tid >> 5);
    const float* row = x + ((size_t)(b * C_ + c)) * N_;
    float s = 0.f, s2 = 0.f;
    for (int n = (tid & 31) * 4; n < N_; n += 128) {
        float4 v = *(const float4*)(row + n);
        s += v.x + v.y + v.z + v.w;
        s2 += v.x * v.x + v.y * v.y + v.z * v.z + v.w * v.w;
    }
    for (int off = 32; off; off >>= 1) {
        s += __shfl_xor(s, off);
        s2 += __shfl_xor(s2, off);
    }
    __shared__ float red[8];
    int wid = tid >> 6;
    if ((tid & 63) == 0) { red[wid] = s; red[4 + wid] = s2; }
    __syncthreads();
    if (tid == 0) {
        float S = red[0] + red[1] + red[2] + red[3];
        float S2 = red[4] + red[5] + red[6] + red[7];
        float mean = S * (1.f / 32768.f);
        float var = S2 * (1.f / 32768.f) - mean * mean;
        gstats[blk * 2] = mean;
        gstats[blk * 2 + 1] = rsqrtf(var + 1e-6f);
    }
}

// ---------------------------------------------------------------------------
// Kernel 2: apply GroupNorm + transpose [b][c][n] fp32 -> [b*n][c] bf16.
// ---------------------------------------------------------------------------
__global__ __launch_bounds__(256) void gn_apply(const float* __restrict__ x,
                                                const float* __restrict__ gsc,
                                                const float* __restrict__ gbi,
                                                const float* __restrict__ gstats,
                                                bf16* __restrict__ hn) {
    __shared__ float tile[32][33];
    int b = blockIdx.z, c0 = blockIdx.y * 32, n0 = blockIdx.x * 32;
    int tx = threadIdx.x & 31, ty = threadIdx.x >> 5;
    for (int i = 0; i < 4; i++) {
        int cl = ty + i * 8;
        int c = c0 + cl;
        int g = c >> 3;
        float mean = gstats[(b * G_ + g) * 2];
        float rstd = gstats[(b * G_ + g) * 2 + 1];
        float sc = gsc[c] * rstd;
        float bs = gbi[c] - mean * sc;
        float v = x[((size_t)(b * C_ + c)) * N_ + n0 + tx];
        tile[cl][tx] = v * sc + bs;
    }
    __syncthreads();
    for (int i = 0; i < 4; i++) {
        int nl = ty + i * 8;
        hn[((size_t)(b * N_ + n0 + nl)) * C_ + c0 + tx] = (bf16)tile[tx][nl];
    }
}

// ---------------------------------------------------------------------------
// Kernel 3: convert the four 256x256 fp32 weight matrices to bf16 once.
// ---------------------------------------------------------------------------
__global__ __launch_bounds__(256) void cvt_w(const float* __restrict__ wq,
                                             const float* __restrict__ wk,
                                             const float* __restrict__ wv,
                                             const float* __restrict__ wp,
                                             bf16* __restrict__ dst) {
    int i = blockIdx.x * 256 + threadIdx.x;
    dst[i] = (bf16)wq[i];
    dst[65536 + i] = (bf16)wk[i];
    dst[131072 + i] = (bf16)wv[i];
    dst[196608 + i] = (bf16)wp[i];
}

// ---------------------------------------------------------------------------
// Kernel 4: merged Q+K+V NT GEMM. Stages the A (hn) tile ONCE for all three
// weight matrices. Epilogue writes fp8 directly:
//   q8/k8: token-major, sigma channel permutation baked in.
//   v8:    channel-major, pi' key permutation within each 32-key block:
//          pos(k) = ((k&12)<<1) | ((k&16)>>2) | (k&3)
//          (matches the in-register P layout of the swapped-QK^T attention:
//           lane lq holds keys {lq*4+j, 16+lq*4+j} in A-frag slots lq*8+{j,4+j})
// ---------------------------------------------------------------------------
__global__ __launch_bounds__(256) void gemm_qkv(const bf16* __restrict__ A,
                                                const bf16* __restrict__ Wq,
                                                const bf16* __restrict__ Wk,
                                                const bf16* __restrict__ Wv,
                                                const float* __restrict__ bq,
                                                const float* __restrict__ bk,
                                                const float* __restrict__ bv,
                                                u8* __restrict__ q8,
                                                u8* __restrict__ k8,
                                                u8* __restrict__ v8) {
    __shared__ __align__(16) bf16 As[64][32];
    __shared__ __align__(16) bf16 Wqs[64][32];
    __shared__ __align__(16) bf16 Wks[64][32];
    __shared__ __align__(16) bf16 Wvs[64][32];
    int m0 = blockIdx.x * 64;  // token
    int n0 = blockIdx.y * 64;  // out channel
    int tid = threadIdx.x;
    int wv_ = tid >> 6, lane = tid & 63, lr = lane & 15, lq = lane >> 4;
    int wm = (wv_ & 1) * 32, wn = (wv_ >> 1) * 32;
    int sr = tid >> 2, sk = (tid & 3) * 8;  // LDS byte offset == tid*16 (linear)
    f32x4 qacc[2][2] = {}, kacc[2][2] = {}, vacc[2][2] = {};
    for (int kk = 0; kk < C_; kk += 32) {
        __syncthreads();
        gl2lds16(&A[(size_t)(m0 + sr) * C_ + kk + sk], &As[sr][sk]);
        gl2lds16(&Wq[(size_t)(n0 + sr) * C_ + kk + sk], &Wqs[sr][sk]);
        gl2lds16(&Wk[(size_t)(n0 + sr) * C_ + kk + sk], &Wks[sr][sk]);
        gl2lds16(&Wv[(size_t)(n0 + sr) * C_ + kk + sk], &Wvs[sr][sk]);
        __syncthreads();
        bf16x8 a0 = *(const bf16x8*)&As[wm + lr][lq * 8];
        bf16x8 a1 = *(const bf16x8*)&As[wm + 16 + lr][lq * 8];
        bf16x8 q0 = *(const bf16x8*)&Wqs[wn + lr][lq * 8];
        bf16x8 q1 = *(const bf16x8*)&Wqs[wn + 16 + lr][lq * 8];
        bf16x8 k0 = *(const bf16x8*)&Wks[wn + lr][lq * 8];
        bf16x8 k1 = *(const bf16x8*)&Wks[wn + 16 + lr][lq * 8];
        bf16x8 v0 = *(const bf16x8*)&Wvs[wn + lr][lq * 8];
        bf16x8 v1 = *(const bf16x8*)&Wvs[wn + 16 + lr][lq * 8];
        qacc[0][0] = mfma16(a0, q0, qacc[0][0]);
        qacc[0][1] = mfma16(a0, q1, qacc[0][1]);
        qacc[1][0] = mfma16(a1, q0, qacc[1][0]);
        qacc[1][1] = mfma16(a1, q1, qacc[1][1]);
        kacc[0][0] = mfma16(a0, k0, kacc[0][0]);
        kacc[0][1] = mfma16(a0, k1, kacc[0][1]);
        kacc[1][0] = mfma16(a1, k0, kacc[1][0]);
        kacc[1][1] = mfma16(a1, k1, kacc[1][1]);
        vacc[0][0] = mfma16(a0, v0, vacc[0][0]);
        vacc[0][1] = mfma16(a0, v1, vacc[0][1]);
        vacc[1][0] = mfma16(a1, v0, vacc[1][0]);
        vacc[1][1] = mfma16(a1, v1, vacc[1][1]);
    }
    for (int i = 0; i < 2; i++)
        for (int j = 0; j < 2; j++) {
            int col = n0 + wn + j * 16 + lr;
            // inverse sigma: write channel col to fp8 position p
            int p = (col & 0xC0) | ((col & 0x18) << 1) | ((col & 0x20) >> 2) | (col & 7);
            float bvq = bq[col], bvk = bk[col], bvv = bv[col];
            for (int r = 0; r < 4; r++) {
                int row = m0 + wm + i * 16 + lq * 4 + r;
                q8[(size_t)row * C_ + p] = (u8)f32_to_fp8(qacc[i][j][r] + bvq);
                k8[(size_t)row * C_ + p] = (u8)f32_to_fp8(kacc[i][j][r] + bvk);
                int bb = row >> 12, n = row & (N_ - 1);
                int n5 = n & 31;
                v8[((size_t)(bb * C_ + col)) * N_ + (n & ~31) +
                   (((n5 & 12) << 1) | ((n5 & 16) >> 2) | (n5 & 3))] =
                    (u8)f32_to_fp8(vacc[i][j][r] + bvv);
            }
        }
}

// ---------------------------------------------------------------------------
// Kernel 6: fp8 flash attention, fixed-max softmax, block-level split-K.
//   SWAPPED QK^T (S^T = mfma(K, Q)): output col = query, row = key, so each
//   lane holds 8 key-values for ONE query row -> P packed to fp8 fully
//   in-register (A-fragment byte slot lq*8+j <-> key via pi'), feeding PV
//   directly. No P LDS buffer, no threadfence, LDS = 32 KB.
//   XCD-swizzled grid: each XCD keeps one batch's K/V (4 MB = L2) resident.
// ---------------------------------------------------------------------------
__global__ __launch_bounds__(128, 2) void attn(const u8* __restrict__ q,
                                               const u8* __restrict__ k,
                                               const u8* __restrict__ vT,
                                               bf16* __restrict__ O0,
                                               bf16* __restrict__ O1,
                                               float* __restrict__ lp) {
    __shared__ __align__(16) u8 smem[32768];
    u8* Ks = smem;           // [2][32*256] fp8 = 16 KB
    u8* Vt = smem + 16384;   // [2][256*32] fp8 = 16 KB

    // Bijective XCD swizzle (1024 blocks % 8 == 0): XCD x gets nid x*128..+127
    // = one batch, both halves, all 64 q-tiles -> K/V stays in that XCD's L2.
    int flat = blockIdx.x + (blockIdx.y << 6) + (blockIdx.z << 7);
    int nid = (flat & 7) * 128 + (flat >> 3);
    int q0 = (nid & 63) * 64;
    int h = (nid >> 6) & 1;
    int b = nid >> 7;
    int tid = threadIdx.x;
    int w = tid >> 6, lane = tid & 63, lr = lane & 15, lq = lane >> 4;

    const u8* kglob = k + ((size_t)(b * N_) + h * 2048) * 256;
    const u8* vglob = vT + (size_t)b * C_ * N_ + h * 2048;

    u32 offK[4], offV[4];
#pragma unroll
    for (int j = 0; j < 4; j++) {
        int p = ((w * 4 + j) << 6) + lane;  // 0..511
        int rK = p >> 4, cK = (p & 15) ^ (rK & 15);
        offK[j] = rK * 256 + cK * 16;
        int rV = p >> 1, cV = (p & 1) ^ ((rV >> 2) & 1);
        offV[j] = rV * N_ + cV * 16;
    }

    // Q fragments (fp8, sigma-permuted): [subtile t][tq] b128 = k-steps 2tq,2tq+1.
    i64x2 qf[2][4];
#pragma unroll
    for (int t = 0; t < 2; t++) {
        const u8* qrow = q + ((size_t)(b * N_ + q0 + w * 32 + t * 16 + lr)) * 256;
#pragma unroll
        for (int tq = 0; tq < 4; tq++)
            qf[t][tq] = *(const i64x2*)&qrow[tq * 64 + lq * 16];
    }

    f32x4 oacc[2][16] = {};
    float li[2] = {};

    // Prologue: stage tile 0 into buffer 0.
#pragma unroll
    for (int j = 0; j < 4; j++) {
        gl2lds16(kglob + offK[j], Ks + ((w * 4 + j) << 10));
        gl2lds16(vglob + offV[j], Vt + ((w * 4 + j) << 10));
    }

    for (int mt = 0; mt < 64; mt++) {
        int cur = mt & 1;
        __syncthreads();

        if (mt < 63) {
            const u8* kit = kglob + (size_t)(mt + 1) * 32 * 256;
            const u8* vit = vglob + (mt + 1) * 32;
#pragma unroll
            for (int j = 0; j < 4; j++) {
                gl2lds16(kit + offK[j], Ks + (cur ^ 1) * 8192 + ((w * 4 + j) << 10));
                gl2lds16(vit + offV[j], Vt + (cur ^ 1) * 8192 + ((w * 4 + j) << 10));
            }
        }

        const u8* Kb = Ks + cur * 8192;
        const u8* Vb = Vt + cur * 8192;

        // --- S^T = K Q^T: st[qt][kt], col = query (lr), row = key (lq*4+r) ---
        f32x4 st[2][2] = {};
#pragma unroll
        for (int kt = 0; kt < 2; kt++) {
            int r = kt * 16 + lr;
#pragma unroll
            for (int tq = 0; tq < 4; tq++) {
                i64x2 kf = *(const i64x2*)&Kb[r * 256 + (((tq * 4 + lq) ^ (r & 15)) << 4)];
                st[0][kt] = mfma_fp8(kf.x, qf[0][tq].x, st[0][kt]);
                st[0][kt] = mfma_fp8(kf.y, qf[0][tq].y, st[0][kt]);
                st[1][kt] = mfma_fp8(kf.x, qf[1][tq].x, st[1][kt]);
                st[1][kt] = mfma_fp8(kf.y, qf[1][tq].y, st[1][kt]);
            }
        }

        // --- fixed-max softmax numerators -> fp8 P, packed IN-REGISTER.
        //     Lane holds keys {kt*16 + lq*4 + r} for query lr; A-frag slot
        //     lq*8 + (kt*4 + r) <-> V key position pi'(k). ---
        i64 pf[2];
#pragma unroll
        for (int qt = 0; qt < 2; qt++) {
            float e[2][4];
#pragma unroll
            for (int kt = 0; kt < 2; kt++)
#pragma unroll
                for (int r = 0; r < 4; r++)
                    e[kt][r] = __expf(st[qt][kt][r] * 0.0625f);
            li[qt] += ((e[0][0] + e[0][1]) + (e[0][2] + e[0][3])) +
                      ((e[1][0] + e[1][1]) + (e[1][2] + e[1][3]));
            u32 lo = (fp8_fast(e[0][0]) & 0xff) | ((fp8_fast(e[0][1]) & 0xff) << 8) |
                     ((fp8_fast(e[0][2]) & 0xff) << 16) | (fp8_fast(e[0][3]) << 24);
            u32 hi = (fp8_fast(e[1][0]) & 0xff) | ((fp8_fast(e[1][1]) & 0xff) << 8) |
                     ((fp8_fast(e[1][2]) & 0xff) << 16) | (fp8_fast(e[1][3]) << 24);
            pf[qt] = (i64)(((u64)hi << 32) | lo);
        }

        // --- PV: P (32x32) x V (32x256), P straight from registers ---
#pragma unroll
        for (int ct = 0; ct < 16; ct++) {
            int row = ct * 16 + lr;
            i64 vf = *(const i64a*)&Vb[row * 32 + (((lq >> 1) ^ ((row >> 2) & 1)) << 4) +
                                       ((lq & 1) << 3)];
            oacc[0][ct] = mfma_fp8(pf[0], vf, oacc[0][ct]);
            oacc[1][ct] = mfma_fp8(pf[1], vf, oacc[1][ct]);
        }
    }

    // li[qt] holds the partial row-sum for query qt*16+lr (duplicated over lq).
    float lsum[2];
#pragma unroll
    for (int qt = 0; qt < 2; qt++) {
        float s = li[qt];
        s += __shfl_xor(s, 16);
        s += __shfl_xor(s, 32);
        lsum[qt] = s;
    }

    bf16* Op = h ? O1 : O0;
#pragma unroll
    for (int t = 0; t < 2; t++)
#pragma unroll
        for (int ct = 0; ct < 16; ct++)
#pragma unroll
            for (int r = 0; r < 4; r++)
                Op[((size_t)(b * N_ + q0 + w * 32 + t * 16 + lq * 4 + r)) * C_ + ct * 16 + lr] =
                    (bf16)oacc[t][ct][r];
    if (lq == 0) {
        float* lrow = lp + ((size_t)(h * B_ + b)) * N_ + q0 + w * 32;
#pragma unroll
        for (int qt = 0; qt < 2; qt++) lrow[qt * 16 + lr] = lsum[qt];
    }
}

// ---------------------------------------------------------------------------
// Kernel 7: proj + residual, split-K combine fused into A-staging.
// ---------------------------------------------------------------------------
__global__ __launch_bounds__(256) void proj_res(const bf16* __restrict__ W,
                                                const bf16* __restrict__ O0,
                                                const bf16* __restrict__ O1,
                                                const float* __restrict__ lp,
                                                const float* __restrict__ bias,
                                                const float* __restrict__ x,
                                                float* __restrict__ out) {
    __shared__ __align__(16) bf16 Ws[64][32];
    __shared__ __align__(16) bf16 As[64][32];
    int m0 = blockIdx.x * 64;  // o
    int n0 = blockIdx.y * 64;  // token
    int tid = threadIdx.x;
    int wv_ = tid >> 6, lane = tid & 63, lr = lane & 15, lq = lane >> 4;
    int wm = (wv_ & 1) * 32, wn = (wv_ >> 1) * 32;
    int sr = tid >> 2, sk = (tid & 3) * 8;
    int T = n0 + sr, bb = T >> 12, nn = T & (N_ - 1);
    float inv = 1.f / (lp[(size_t)bb * N_ + nn] + lp[(size_t)(B_ + bb) * N_ + nn]);
    f32x4 acc[2][2] = {};
    for (int kk = 0; kk < C_; kk += 32) {
        __syncthreads();
        gl2lds16(&W[(size_t)(m0 + sr) * C_ + kk + sk], &Ws[sr][sk]);
        bf16x8 o0 = *(const bf16x8*)&O0[(size_t)T * C_ + kk + sk];
        bf16x8 o1 = *(const bf16x8*)&O1[(size_t)T * C_ + kk + sk];
        bf16x8 cm;
#pragma unroll
        for (int e = 0; e < 8; e++) cm[e] = (bf16)(((float)o0[e] + (float)o1[e]) * inv);
        *(bf16x8*)&As[sr][sk] = cm;
        __syncthreads();
        bf16x8 a0 = *(const bf16x8*)&Ws[wm + lr][lq * 8];
        bf16x8 a1 = *(const bf16x8*)&Ws[wm + 16 + lr][lq * 8];
        bf16x8 b0 = *(const bf16x8*)&As[wn + lr][lq * 8];
        bf16x8 b1 = *(const bf16x8*)&As[wn + 16 + lr][lq * 8];
        acc[0][0] = mfma16(a0, b0, acc[0][0]);
        acc[0][1] = mfma16(a0, b1, acc[0][1]);
        acc[1][0] = mfma16(a1, b0, acc[1][0]);
        acc[1][1] = mfma16(a1, b1, acc[1][1]);
    }
    for (int i = 0; i < 2; i++)
        for (int j = 0; j < 2; j++) {
            int Tt = n0 + wn + j * 16 + lr;
            int b = Tt >> 12, n = Tt & (N_ - 1);
            for (int r = 0; r < 4; r++) {
                int o = m0 + wm + i * 16 + lq * 4 + r;
                size_t idx = ((size_t)(b * C_ + o)) * N_ + n;
                out[idx] = x[idx] + acc[i][j][r] + bias[o];
            }
        }
}

// ---------------------------------------------------------------------------
extern "C" void kernel_launch(void* const* d_in, const int* in_sizes, int n_in,
                              void* d_out, int out_size, void* d_ws, size_t ws_size,
                              hipStream_t stream) {
    const float* x = (const float*)d_in[0];
    const float* gsc = (const float*)d_in[1];
    const float* gbi = (const float*)d_in[2];
    const float* wq = (const float*)d_in[3];
    const float* bq = (const float*)d_in[4];
    const float* wk = (const float*)d_in[5];
    const float* bk = (const float*)d_in[6];
    const float* wv = (const float*)d_in[7];
    const float* bv = (const float*)d_in[8];
    const float* wp = (const float*)d_in[9];
    const float* bp = (const float*)d_in[10];
    float* out = (float*)d_out;

    const size_t SZ = (size_t)B_ * N_ * C_;  // 8388608 elements
    char* ws = (char*)d_ws;
    float* gstats = (float*)ws;              // 4 KB slot
    bf16* wb = (bf16*)(ws + 4096);           // 512 KB
    char* base = ws + 4096 + 524288;
    // Layout (59.5 MB total):
    //   [0,      SZ*2) hn  (bf16)  -> reused as O0 after gemm_qkv
    //   [SZ*2,   SZ*3) q8  (fp8)
    //   [SZ*3,   SZ*4) k8  (fp8)
    //   [SZ*4,   SZ*5) v8  (fp8)
    //   [SZ*5,   SZ*7) O1  (bf16)
    //   [SZ*7,  +256K) lpart (f32)
    bf16* hn = (bf16*)base;
    u8* q8 = (u8*)(base + SZ * 2);
    u8* k8 = (u8*)(base + SZ * 3);
    u8* v8 = (u8*)(base + SZ * 4);
    bf16* O0 = (bf16*)base;                  // hn dead after gemm_qkv
    bf16* O1 = (bf16*)(base + SZ * 5);
    float* lpart = (float*)(base + SZ * 7);

    cvt_w<<<256, 256, 0, stream>>>(wq, wk, wv, wp, wb);
    gn_stats<<<B_ * G_, 256, 0, stream>>>(x, gstats);
    gn_apply<<<dim3(N_ / 32, C_ / 32, B_), 256, 0, stream>>>(x, gsc, gbi, gstats, hn);
    gemm_qkv<<<dim3(B_ * N_ / 64, C_ / 64), 256, 0, stream>>>(
        hn, wb, wb + 65536, wb + 131072, bq, bk, bv, q8, k8, v8);
    attn<<<dim3(N_ / 64, 2, B_), 128, 0, stream>>>(q8, k8, v8, O0, O1, lpart);
    proj_res<<<dim3(C_ / 64, B_ * N_ / 64), 256, 0, stream>>>(
        wb + 196608, O0, O1, lpart, bp, x, out);
}

// Round 3
// 293.596 us; speedup vs baseline: 1.1033x; 1.0443x over previous
//
#include <hip/hip_runtime.h>

#define B_ 8
#define C_ 256
#define N_ 4096
#define G_ 32

typedef __bf16 bf16;
typedef __bf16 bf16x8 __attribute__((ext_vector_type(8)));
typedef float f32x4 __attribute__((ext_vector_type(4)));
typedef long i64;
typedef long i64x2 __attribute__((ext_vector_type(2)));
typedef unsigned int u32;
typedef unsigned char u8;
typedef unsigned short u16;
typedef unsigned long long u64;
// may_alias: LDS V-tile bytes are written by global_load_lds and read as i64.
typedef long __attribute__((may_alias)) i64a;

__device__ __forceinline__ f32x4 mfma16(bf16x8 a, bf16x8 b, f32x4 c) {
    return __builtin_amdgcn_mfma_f32_16x16x32_bf16(a, b, c, 0, 0, 0);
}
__device__ __forceinline__ f32x4 mfma_fp8(i64 a, i64 b, f32x4 c) {
    return __builtin_amdgcn_mfma_f32_16x16x32_fp8_fp8(a, b, c, 0, 0, 0);
}

typedef __attribute__((address_space(1))) const void* gas_t;
typedef __attribute__((address_space(3))) void* las_t;
__device__ __forceinline__ void gl2lds16(const void* g, void* l) {
    __builtin_amdgcn_global_load_lds((gas_t)g, (las_t)l, 16, 0, 0);
}

// Full-range f32 -> OCP e4m3fn (NaN-free by construction).
__device__ __forceinline__ u32 f32_to_fp8(float x) {
    union { float f; u32 u; } c;
    c.f = x;
    u32 s = (c.u >> 24) & 0x80;
    u32 m = (c.u & 0x7fffffff) + 0x00080000;
    int e = (int)(m >> 23) - 127;
    if (e < -6) return s;
    if (e > 8) return s | 0x7e;
    u32 v = ((u32)(e + 7) << 3) | ((m >> 20) & 7);
    if (v > 0x7e) v = 0x7e;
    return s | v;
}
// 3-op converter for known-positive x in [2^-6, 2^8): exp() outputs only.
// Low 8 bits valid; callers mask.
__device__ __forceinline__ u32 fp8_fast(float x) {
    union { float f; u32 u; } c;
    c.f = x;
    return ((c.u + 0x00080000u) >> 20) - 960u;
}

// ---------------------------------------------------------------------------
// Kernel 1: GroupNorm statistics. One block per (batch, group).
// ---------------------------------------------------------------------------
__global__ __launch_bounds__(256) void gn_stats(const float* __restrict__ x,
                                                float* __restrict__ gstats) {
    int blk = blockIdx.x;  // b*32 + g
    int b = blk >> 5, g = blk & 31;
    int tid = threadIdx.x;
    int c = g * 8 + (tid >> 5);
    const float* row = x + ((size_t)(b * C_ + c)) * N_;
    float s = 0.f, s2 = 0.f;
    for (int n = (tid & 31) * 4; n < N_; n += 128) {
        float4 v = *(const float4*)(row + n);
        s += v.x + v.y + v.z + v.w;
        s2 += v.x * v.x + v.y * v.y + v.z * v.z + v.w * v.w;
    }
    for (int off = 32; off; off >>= 1) {
        s += __shfl_xor(s, off);
        s2 += __shfl_xor(s2, off);
    }
    __shared__ float red[8];
    int wid = tid >> 6;
    if ((tid & 63) == 0) { red[wid] = s; red[4 + wid] = s2; }
    __syncthreads();
    if (tid == 0) {
        float S = red[0] + red[1] + red[2] + red[3];
        float S2 = red[4] + red[5] + red[6] + red[7];
        float mean = S * (1.f / 32768.f);
        float var = S2 * (1.f / 32768.f) - mean * mean;
        gstats[blk * 2] = mean;
        gstats[blk * 2 + 1] = rsqrtf(var + 1e-6f);
    }
}

// ---------------------------------------------------------------------------
// Kernel 2: apply GroupNorm + transpose [b][c][n] fp32 -> [b*n][c] bf16.
// ---------------------------------------------------------------------------
__global__ __launch_bounds__(256) void gn_apply(const float* __restrict__ x,
                                                const float* __restrict__ gsc,
                                                const float* __restrict__ gbi,
                                                const float* __restrict__ gstats,
                                                bf16* __restrict__ hn) {
    __shared__ float tile[32][33];
    int b = blockIdx.z, c0 = blockIdx.y * 32, n0 = blockIdx.x * 32;
    int tx = threadIdx.x & 31, ty = threadIdx.x >> 5;
    for (int i = 0; i < 4; i++) {
        int cl = ty + i * 8;
        int c = c0 + cl;
        int g = c >> 3;
        float mean = gstats[(b * G_ + g) * 2];
        float rstd = gstats[(b * G_ + g) * 2 + 1];
        float sc = gsc[c] * rstd;
        float bs = gbi[c] - mean * sc;
        float v = x[((size_t)(b * C_ + c)) * N_ + n0 + tx];
        tile[cl][tx] = v * sc + bs;
    }
    __syncthreads();
    for (int i = 0; i < 4; i++) {
        int nl = ty + i * 8;
        hn[((size_t)(b * N_ + n0 + nl)) * C_ + c0 + tx] = (bf16)tile[tx][nl];
    }
}

// ---------------------------------------------------------------------------
// Kernel 3: convert the four 256x256 fp32 weight matrices to bf16 once.
// ---------------------------------------------------------------------------
__global__ __launch_bounds__(256) void cvt_w(const float* __restrict__ wq,
                                             const float* __restrict__ wk,
                                             const float* __restrict__ wv,
                                             const float* __restrict__ wp,
                                             bf16* __restrict__ dst) {
    int i = blockIdx.x * 256 + threadIdx.x;
    dst[i] = (bf16)wq[i];
    dst[65536 + i] = (bf16)wk[i];
    dst[131072 + i] = (bf16)wv[i];
    dst[196608 + i] = (bf16)wp[i];
}

// ---------------------------------------------------------------------------
// Kernel 4: merged Q+K+V NT GEMM. Stages the A (hn) tile ONCE for all three
// weight matrices. Epilogue writes fp8 directly:
//   q8/k8: token-major, sigma channel permutation baked in.
//   v8:    TILED layout: [b][ktile(=n>>5)][8192 B], tile = [lqg][ch2][clow][8k]
//          byte offset within tile for (channel c, key k5):
//            m = pi'(k5) = ((k5&12)<<1)|((k5&16)>>2)|(k5&3)
//            off = (m>>3)*2048 + c*8 + (m&7)
//          -> attn's PV ds_read_b64 at lq*2048 + ch*8 is bank-conflict-free,
//             and the gl2lds staging source is fully linear/coalesced.
// ---------------------------------------------------------------------------
__global__ __launch_bounds__(256) void gemm_qkv(const bf16* __restrict__ A,
                                                const bf16* __restrict__ Wq,
                                                const bf16* __restrict__ Wk,
                                                const bf16* __restrict__ Wv,
                                                const float* __restrict__ bq,
                                                const float* __restrict__ bk,
                                                const float* __restrict__ bv,
                                                u8* __restrict__ q8,
                                                u8* __restrict__ k8,
                                                u8* __restrict__ v8) {
    __shared__ __align__(16) bf16 As[64][32];
    __shared__ __align__(16) bf16 Wqs[64][32];
    __shared__ __align__(16) bf16 Wks[64][32];
    __shared__ __align__(16) bf16 Wvs[64][32];
    int m0 = blockIdx.x * 64;  // token
    int n0 = blockIdx.y * 64;  // out channel
    int tid = threadIdx.x;
    int wv_ = tid >> 6, lane = tid & 63, lr = lane & 15, lq = lane >> 4;
    int wm = (wv_ & 1) * 32, wn = (wv_ >> 1) * 32;
    int sr = tid >> 2, sk = (tid & 3) * 8;  // LDS byte offset == tid*16 (linear)
    f32x4 qacc[2][2] = {}, kacc[2][2] = {}, vacc[2][2] = {};
    for (int kk = 0; kk < C_; kk += 32) {
        __syncthreads();
        gl2lds16(&A[(size_t)(m0 + sr) * C_ + kk + sk], &As[sr][sk]);
        gl2lds16(&Wq[(size_t)(n0 + sr) * C_ + kk + sk], &Wqs[sr][sk]);
        gl2lds16(&Wk[(size_t)(n0 + sr) * C_ + kk + sk], &Wks[sr][sk]);
        gl2lds16(&Wv[(size_t)(n0 + sr) * C_ + kk + sk], &Wvs[sr][sk]);
        __syncthreads();
        bf16x8 a0 = *(const bf16x8*)&As[wm + lr][lq * 8];
        bf16x8 a1 = *(const bf16x8*)&As[wm + 16 + lr][lq * 8];
        bf16x8 q0 = *(const bf16x8*)&Wqs[wn + lr][lq * 8];
        bf16x8 q1 = *(const bf16x8*)&Wqs[wn + 16 + lr][lq * 8];
        bf16x8 k0 = *(const bf16x8*)&Wks[wn + lr][lq * 8];
        bf16x8 k1 = *(const bf16x8*)&Wks[wn + 16 + lr][lq * 8];
        bf16x8 v0 = *(const bf16x8*)&Wvs[wn + lr][lq * 8];
        bf16x8 v1 = *(const bf16x8*)&Wvs[wn + 16 + lr][lq * 8];
        qacc[0][0] = mfma16(a0, q0, qacc[0][0]);
        qacc[0][1] = mfma16(a0, q1, qacc[0][1]);
        qacc[1][0] = mfma16(a1, q0, qacc[1][0]);
        qacc[1][1] = mfma16(a1, q1, qacc[1][1]);
        kacc[0][0] = mfma16(a0, k0, kacc[0][0]);
        kacc[0][1] = mfma16(a0, k1, kacc[0][1]);
        kacc[1][0] = mfma16(a1, k0, kacc[1][0]);
        kacc[1][1] = mfma16(a1, k1, kacc[1][1]);
        vacc[0][0] = mfma16(a0, v0, vacc[0][0]);
        vacc[0][1] = mfma16(a0, v1, vacc[0][1]);
        vacc[1][0] = mfma16(a1, v0, vacc[1][0]);
        vacc[1][1] = mfma16(a1, v1, vacc[1][1]);
    }
    for (int i = 0; i < 2; i++)
        for (int j = 0; j < 2; j++) {
            int col = n0 + wn + j * 16 + lr;
            // inverse sigma: write channel col to fp8 position p
            int p = (col & 0xC0) | ((col & 0x18) << 1) | ((col & 0x20) >> 2) | (col & 7);
            float bvq = bq[col], bvk = bk[col], bvv = bv[col];
            for (int r = 0; r < 4; r++) {
                int row = m0 + wm + i * 16 + lq * 4 + r;
                q8[(size_t)row * C_ + p] = (u8)f32_to_fp8(qacc[i][j][r] + bvq);
                k8[(size_t)row * C_ + p] = (u8)f32_to_fp8(kacc[i][j][r] + bvk);
                int bb = row >> 12, n = row & (N_ - 1);
                int k5 = n & 31;
                int m = ((k5 & 12) << 1) | ((k5 & 16) >> 2) | (k5 & 3);
                v8[((size_t)(bb * 128 + (n >> 5))) * 8192 + ((m >> 3) << 11) +
                   (col << 3) + (m & 7)] = (u8)f32_to_fp8(vacc[i][j][r] + bvv);
            }
        }
}

// ---------------------------------------------------------------------------
// Kernel 6: fp8 flash attention, fixed-max softmax, block-level split-K.
//   Software-pipelined: per iteration t computes QK^T(t+1)+softmax(t+1) into
//   pf_next (independent VALU work) while PV(t) consumes pf_prev -> softmax
//   VALU hides under the MFMA drain instead of serializing between bursts.
//   K: 2 LDS buffers (read t+1, stage t+2). V: 3 buffers (read t, stage t+2).
//   LDS = 40 KB -> still 4 blocks/CU. V tiles are contiguous 8 KB in the new
//   [lqg][ch][8key] layout: PV ds_read_b64 bank-conflict-free, gl2lds linear.
// ---------------------------------------------------------------------------
__global__ __launch_bounds__(128, 2) void attn(const u8* __restrict__ q,
                                               const u8* __restrict__ k,
                                               const u8* __restrict__ vT,
                                               bf16* __restrict__ O0,
                                               bf16* __restrict__ O1,
                                               float* __restrict__ lp) {
    __shared__ __align__(16) u8 smem[40960];
    u8* Ks = smem;           // [2][8192]
    u8* Vt = smem + 16384;   // [3][8192]

    // Bijective XCD swizzle (1024 blocks % 8 == 0): XCD x gets one batch.
    int flat = blockIdx.x + (blockIdx.y << 6) + (blockIdx.z << 7);
    int nid = (flat & 7) * 128 + (flat >> 3);
    int q0 = (nid & 63) * 64;
    int h = (nid >> 6) & 1;
    int b = nid >> 7;
    int tid = threadIdx.x;
    int w = tid >> 6, lane = tid & 63, lr = lane & 15, lq = lane >> 4;

    const u8* kglob = k + ((size_t)(b * N_) + h * 2048) * 256;
    const u8* vglob = vT + ((size_t)(b * 128) + h * 64) * 8192;

    // Staging offsets: K keeps the xor-swizzled layout; V is linear (tiled).
    u32 offK[4], offV[4];
#pragma unroll
    for (int j = 0; j < 4; j++) {
        int p = ((w * 4 + j) << 6) + lane;  // 0..511
        int rK = p >> 4, cK = (p & 15) ^ (rK & 15);
        offK[j] = rK * 256 + cK * 16;
        offV[j] = (u32)p << 4;
    }

    // Loop-invariant LDS read offsets.
    u32 kq[8];
#pragma unroll
    for (int kt = 0; kt < 2; kt++)
#pragma unroll
        for (int tq = 0; tq < 4; tq++)
            kq[kt * 4 + tq] = (u32)((kt * 16 + lr) * 256 + (((tq * 4 + lq) ^ lr) << 4));
    u32 vbase = (u32)(lq * 2048 + lr * 8);

    // Q fragments (fp8, sigma-permuted): [subtile t][tq] b128 = k-steps 2tq,2tq+1.
    i64x2 qf[2][4];
#pragma unroll
    for (int t = 0; t < 2; t++) {
        const u8* qrow = q + ((size_t)(b * N_ + q0 + w * 32 + t * 16 + lr)) * 256;
#pragma unroll
        for (int tq = 0; tq < 4; tq++)
            qf[t][tq] = *(const i64x2*)&qrow[tq * 64 + lq * 16];
    }

    f32x4 oacc[2][16] = {};
    float li[2] = {};
    i64 pfA[2], pfB[2];

    auto STAGE = [&](int t, u32 kdst, u32 vdst) {
        const u8* kg = kglob + (size_t)t * 8192;
        const u8* vg = vglob + (size_t)t * 8192;
#pragma unroll
        for (int j = 0; j < 4; j++) {
            gl2lds16(kg + offK[j], Ks + kdst + ((w * 4 + j) << 10));
            gl2lds16(vg + offV[j], Vt + vdst + ((w * 4 + j) << 10));
        }
    };
    // S^T = K Q^T for one 32-key tile, then fixed-max softmax -> fp8 P packed
    // in-register (A-frag slot lq*8+(kt*4+r) <-> key via pi').
    auto QKT_SM = [&](u32 krd, i64 (&pf)[2]) {
        f32x4 st[2][2] = {};
#pragma unroll
        for (int kt = 0; kt < 2; kt++)
#pragma unroll
            for (int tq = 0; tq < 4; tq++) {
                i64x2 kf = *(const i64x2*)&Ks[krd + kq[kt * 4 + tq]];
                st[0][kt] = mfma_fp8(kf.x, qf[0][tq].x, st[0][kt]);
                st[0][kt] = mfma_fp8(kf.y, qf[0][tq].y, st[0][kt]);
                st[1][kt] = mfma_fp8(kf.x, qf[1][tq].x, st[1][kt]);
                st[1][kt] = mfma_fp8(kf.y, qf[1][tq].y, st[1][kt]);
            }
#pragma unroll
        for (int qt = 0; qt < 2; qt++) {
            float e[2][4];
#pragma unroll
            for (int kt = 0; kt < 2; kt++)
#pragma unroll
                for (int r = 0; r < 4; r++)
                    e[kt][r] = __expf(st[qt][kt][r] * 0.0625f);
            li[qt] += ((e[0][0] + e[0][1]) + (e[0][2] + e[0][3])) +
                      ((e[1][0] + e[1][1]) + (e[1][2] + e[1][3]));
            u32 lo = (fp8_fast(e[0][0]) & 0xff) | ((fp8_fast(e[0][1]) & 0xff) << 8) |
                     ((fp8_fast(e[0][2]) & 0xff) << 16) | (fp8_fast(e[0][3]) << 24);
            u32 hi = (fp8_fast(e[1][0]) & 0xff) | ((fp8_fast(e[1][1]) & 0xff) << 8) |
                     ((fp8_fast(e[1][2]) & 0xff) << 16) | (fp8_fast(e[1][3]) << 24);
            pf[qt] = (i64)(((u64)hi << 32) | lo);
        }
    };
    auto PV = [&](u32 vrd, i64 (&pf)[2]) {
#pragma unroll
        for (int ct = 0; ct < 16; ct++) {
            i64 vf = *(const i64a*)&Vt[vrd + vbase + ct * 128];
            oacc[0][ct] = mfma_fp8(pf[0], vf, oacc[0][ct]);
            oacc[1][ct] = mfma_fp8(pf[1], vf, oacc[1][ct]);
        }
    };

    // Prologue: stage tiles 0 and 1; compute S(0)+softmax(0) -> pfA.
    STAGE(0, 0, 0);
    STAGE(1, 8192, 8192);
    __syncthreads();
    QKT_SM(0, pfA);

    u32 vr0 = 0, vr1 = 8192, vr2 = 16384;
    for (int mt = 0; mt < 62; mt += 2) {
        // even t=mt: read K@8192 (=K(t+1)), stage K(t+2)@0; V read vr0, stage vr2
        __syncthreads();
        STAGE(mt + 2, 0, vr2);
        __builtin_amdgcn_s_setprio(1);
        QKT_SM(8192, pfB);
        PV(vr0, pfA);
        __builtin_amdgcn_s_setprio(0);
        { u32 t = vr0; vr0 = vr1; vr1 = vr2; vr2 = t; }
        // odd t=mt+1: read K@0, stage K(t+2)@8192
        __syncthreads();
        STAGE(mt + 3, 8192, vr2);
        __builtin_amdgcn_s_setprio(1);
        QKT_SM(0, pfA);
        PV(vr0, pfB);
        __builtin_amdgcn_s_setprio(0);
        { u32 t = vr0; vr0 = vr1; vr1 = vr2; vr2 = t; }
    }
    // t = 62: read K@8192 (=K63); no staging left.
    __syncthreads();
    __builtin_amdgcn_s_setprio(1);
    QKT_SM(8192, pfB);
    PV(vr0, pfA);
    { u32 t = vr0; vr0 = vr1; vr1 = vr2; vr2 = t; }
    // PV(63).
    PV(vr0, pfB);
    __builtin_amdgcn_s_setprio(0);

    // li[qt] holds the partial row-sum for query qt*16+lr (duplicated over lq).
    float lsum[2];
#pragma unroll
    for (int qt = 0; qt < 2; qt++) {
        float s = li[qt];
        s += __shfl_xor(s, 16);
        s += __shfl_xor(s, 32);
        lsum[qt] = s;
    }

    bf16* Op = h ? O1 : O0;
#pragma unroll
    for (int t = 0; t < 2; t++)
#pragma unroll
        for (int ct = 0; ct < 16; ct++)
#pragma unroll
            for (int r = 0; r < 4; r++)
                Op[((size_t)(b * N_ + q0 + w * 32 + t * 16 + lq * 4 + r)) * C_ + ct * 16 + lr] =
                    (bf16)oacc[t][ct][r];
    if (lq == 0) {
        float* lrow = lp + ((size_t)(h * B_ + b)) * N_ + q0 + w * 32;
#pragma unroll
        for (int qt = 0; qt < 2; qt++) lrow[qt * 16 + lr] = lsum[qt];
    }
}

// ---------------------------------------------------------------------------
// Kernel 7: proj + residual, split-K combine fused into A-staging.
// ---------------------------------------------------------------------------
__global__ __launch_bounds__(256) void proj_res(const bf16* __restrict__ W,
                                                const bf16* __restrict__ O0,
                                                const bf16* __restrict__ O1,
                                                const float* __restrict__ lp,
                                                const float* __restrict__ bias,
                                                const float* __restrict__ x,
                                                float* __restrict__ out) {
    __shared__ __align__(16) bf16 Ws[64][32];
    __shared__ __align__(16) bf16 As[64][32];
    int m0 = blockIdx.x * 64;  // o
    int n0 = blockIdx.y * 64;  // token
    int tid = threadIdx.x;
    int wv_ = tid >> 6, lane = tid & 63, lr = lane & 15, lq = lane >> 4;
    int wm = (wv_ & 1) * 32, wn = (wv_ >> 1) * 32;
    int sr = tid >> 2, sk = (tid & 3) * 8;
    int T = n0 + sr, bb = T >> 12, nn = T & (N_ - 1);
    float inv = 1.f / (lp[(size_t)bb * N_ + nn] + lp[(size_t)(B_ + bb) * N_ + nn]);
    f32x4 acc[2][2] = {};
    for (int kk = 0; kk < C_; kk += 32) {
        __syncthreads();
        gl2lds16(&W[(size_t)(m0 + sr) * C_ + kk + sk], &Ws[sr][sk]);
        bf16x8 o0 = *(const bf16x8*)&O0[(size_t)T * C_ + kk + sk];
        bf16x8 o1 = *(const bf16x8*)&O1[(size_t)T * C_ + kk + sk];
        bf16x8 cm;
#pragma unroll
        for (int e = 0; e < 8; e++) cm[e] = (bf16)(((float)o0[e] + (float)o1[e]) * inv);
        *(bf16x8*)&As[sr][sk] = cm;
        __syncthreads();
        bf16x8 a0 = *(const bf16x8*)&Ws[wm + lr][lq * 8];
        bf16x8 a1 = *(const bf16x8*)&Ws[wm + 16 + lr][lq * 8];
        bf16x8 b0 = *(const bf16x8*)&As[wn + lr][lq * 8];
        bf16x8 b1 = *(const bf16x8*)&As[wn + 16 + lr][lq * 8];
        acc[0][0] = mfma16(a0, b0, acc[0][0]);
        acc[0][1] = mfma16(a0, b1, acc[0][1]);
        acc[1][0] = mfma16(a1, b0, acc[1][0]);
        acc[1][1] = mfma16(a1, b1, acc[1][1]);
    }
    for (int i = 0; i < 2; i++)
        for (int j = 0; j < 2; j++) {
            int Tt = n0 + wn + j * 16 + lr;
            int b = Tt >> 12, n = Tt & (N_ - 1);
            for (int r = 0; r < 4; r++) {
                int o = m0 + wm + i * 16 + lq * 4 + r;
                size_t idx = ((size_t)(b * C_ + o)) * N_ + n;
                out[idx] = x[idx] + acc[i][j][r] + bias[o];
            }
        }
}

// ---------------------------------------------------------------------------
extern "C" void kernel_launch(void* const* d_in, const int* in_sizes, int n_in,
                              void* d_out, int out_size, void* d_ws, size_t ws_size,
                              hipStream_t stream) {
    const float* x = (const float*)d_in[0];
    const float* gsc = (const float*)d_in[1];
    const float* gbi = (const float*)d_in[2];
    const float* wq = (const float*)d_in[3];
    const float* bq = (const float*)d_in[4];
    const float* wk = (const float*)d_in[5];
    const float* bk = (const float*)d_in[6];
    const float* wv = (const float*)d_in[7];
    const float* bv = (const float*)d_in[8];
    const float* wp = (const float*)d_in[9];
    const float* bp = (const float*)d_in[10];
    float* out = (float*)d_out;

    const size_t SZ = (size_t)B_ * N_ * C_;  // 8388608 elements
    char* ws = (char*)d_ws;
    float* gstats = (float*)ws;              // 4 KB slot
    bf16* wb = (bf16*)(ws + 4096);           // 512 KB
    char* base = ws + 4096 + 524288;
    // Layout (59.5 MB total):
    //   [0,      SZ*2) hn  (bf16)  -> reused as O0 after gemm_qkv
    //   [SZ*2,   SZ*3) q8  (fp8)
    //   [SZ*3,   SZ*4) k8  (fp8)
    //   [SZ*4,   SZ*5) v8  (fp8, tiled [b][128][8192])
    //   [SZ*5,   SZ*7) O1  (bf16)
    //   [SZ*7,  +256K) lpart (f32)
    bf16* hn = (bf16*)base;
    u8* q8 = (u8*)(base + SZ * 2);
    u8* k8 = (u8*)(base + SZ * 3);
    u8* v8 = (u8*)(base + SZ * 4);
    bf16* O0 = (bf16*)base;                  // hn dead after gemm_qkv
    bf16* O1 = (bf16*)(base + SZ * 5);
    float* lpart = (float*)(base + SZ * 7);

    cvt_w<<<256, 256, 0, stream>>>(wq, wk, wv, wp, wb);
    gn_stats<<<B_ * G_, 256, 0, stream>>>(x, gstats);
    gn_apply<<<dim3(N_ / 32, C_ / 32, B_), 256, 0, stream>>>(x, gsc, gbi, gstats, hn);
    gemm_qkv<<<dim3(B_ * N_ / 64, C_ / 64), 256, 0, stream>>>(
        hn, wb, wb + 65536, wb + 131072, bq, bk, bv, q8, k8, v8);
    attn<<<dim3(N_ / 64, 2, B_), 128, 0, stream>>>(q8, k8, v8, O0, O1, lpart);
    proj_res<<<dim3(C_ / 64, B_ * N_ / 64), 256, 0, stream>>>(
        wb + 196608, O0, O1, lpart, bp, x, out);
}

// Round 4
// 278.076 us; speedup vs baseline: 1.1649x; 1.0558x over previous
//
#include <hip/hip_runtime.h>

#define B_ 8
#define C_ 256
#define N_ 4096
#define G_ 32

typedef __bf16 bf16;
typedef __bf16 bf16x8 __attribute__((ext_vector_type(8)));
typedef float f32x4 __attribute__((ext_vector_type(4)));
typedef float f32x16 __attribute__((ext_vector_type(16)));
typedef long i64;
typedef long i64x2 __attribute__((ext_vector_type(2)));
typedef long i64x2a __attribute__((ext_vector_type(2), may_alias));
typedef int i32x8 __attribute__((ext_vector_type(8)));
typedef int i32x8a __attribute__((ext_vector_type(8), may_alias));
typedef unsigned int u32;
typedef unsigned char u8;
typedef unsigned short u16;
typedef unsigned long long u64;

__device__ __forceinline__ f32x4 mfma16(bf16x8 a, bf16x8 b, f32x4 c) {
    return __builtin_amdgcn_mfma_f32_16x16x32_bf16(a, b, c, 0, 0, 0);
}
// MX-scaled fp8 MFMA, 32x32x64, unit scales (E8M0 127 = 1.0 in every byte, so
// the opsel byte choice is irrelevant). 2x the non-scaled fp8 rate.
__device__ __forceinline__ f32x16 mfma_mx(i32x8 a, i32x8 b, f32x16 c) {
    return __builtin_amdgcn_mfma_scale_f32_32x32x64_f8f6f4(
        a, b, c, 0 /*A=fp8*/, 0 /*B=fp8*/, 0, 0x7F7F7F7F, 0, 0x7F7F7F7F);
}

typedef __attribute__((address_space(1))) const void* gas_t;
typedef __attribute__((address_space(3))) void* las_t;
__device__ __forceinline__ void gl2lds16(const void* g, void* l) {
    __builtin_amdgcn_global_load_lds((gas_t)g, (las_t)l, 16, 0, 0);
}

// Full-range f32 -> OCP e4m3fn (NaN-free by construction).
__device__ __forceinline__ u32 f32_to_fp8(float x) {
    union { float f; u32 u; } c;
    c.f = x;
    u32 s = (c.u >> 24) & 0x80;
    u32 m = (c.u & 0x7fffffff) + 0x00080000;
    int e = (int)(m >> 23) - 127;
    if (e < -6) return s;
    if (e > 8) return s | 0x7e;
    u32 v = ((u32)(e + 7) << 3) | ((m >> 20) & 7);
    if (v > 0x7e) v = 0x7e;
    return s | v;
}
// 3-op converter for known-positive x in [2^-6, 2^8): exp() outputs only.
__device__ __forceinline__ u32 fp8_fast(float x) {
    union { float f; u32 u; } c;
    c.f = x;
    return ((c.u + 0x00080000u) >> 20) - 960u;
}

// ---------------------------------------------------------------------------
// Kernel 1: GroupNorm statistics. One block per (batch, group).
// ---------------------------------------------------------------------------
__global__ __launch_bounds__(256) void gn_stats(const float* __restrict__ x,
                                                float* __restrict__ gstats) {
    int blk = blockIdx.x;  // b*32 + g
    int b = blk >> 5, g = blk & 31;
    int tid = threadIdx.x;
    int c = g * 8 + (tid >> 5);
    const float* row = x + ((size_t)(b * C_ + c)) * N_;
    float s = 0.f, s2 = 0.f;
    for (int n = (tid & 31) * 4; n < N_; n += 128) {
        float4 v = *(const float4*)(row + n);
        s += v.x + v.y + v.z + v.w;
        s2 += v.x * v.x + v.y * v.y + v.z * v.z + v.w * v.w;
    }
    for (int off = 32; off; off >>= 1) {
        s += __shfl_xor(s, off);
        s2 += __shfl_xor(s2, off);
    }
    __shared__ float red[8];
    int wid = tid >> 6;
    if ((tid & 63) == 0) { red[wid] = s; red[4 + wid] = s2; }
    __syncthreads();
    if (tid == 0) {
        float S = red[0] + red[1] + red[2] + red[3];
        float S2 = red[4] + red[5] + red[6] + red[7];
        float mean = S * (1.f / 32768.f);
        float var = S2 * (1.f / 32768.f) - mean * mean;
        gstats[blk * 2] = mean;
        gstats[blk * 2 + 1] = rsqrtf(var + 1e-6f);
    }
}

// ---------------------------------------------------------------------------
// Kernel 2: apply GroupNorm + transpose [b][c][n] fp32 -> [b*n][c] bf16.
// ---------------------------------------------------------------------------
__global__ __launch_bounds__(256) void gn_apply(const float* __restrict__ x,
                                                const float* __restrict__ gsc,
                                                const float* __restrict__ gbi,
                                                const float* __restrict__ gstats,
                                                bf16* __restrict__ hn) {
    __shared__ float tile[32][33];
    int b = blockIdx.z, c0 = blockIdx.y * 32, n0 = blockIdx.x * 32;
    int tx = threadIdx.x & 31, ty = threadIdx.x >> 5;
    for (int i = 0; i < 4; i++) {
        int cl = ty + i * 8;
        int c = c0 + cl;
        int g = c >> 3;
        float mean = gstats[(b * G_ + g) * 2];
        float rstd = gstats[(b * G_ + g) * 2 + 1];
        float sc = gsc[c] * rstd;
        float bs = gbi[c] - mean * sc;
        float v = x[((size_t)(b * C_ + c)) * N_ + n0 + tx];
        tile[cl][tx] = v * sc + bs;
    }
    __syncthreads();
    for (int i = 0; i < 4; i++) {
        int nl = ty + i * 8;
        hn[((size_t)(b * N_ + n0 + nl)) * C_ + c0 + tx] = (bf16)tile[tx][nl];
    }
}

// ---------------------------------------------------------------------------
// Kernel 3: convert the four 256x256 fp32 weight matrices to bf16 once.
// ---------------------------------------------------------------------------
__global__ __launch_bounds__(256) void cvt_w(const float* __restrict__ wq,
                                             const float* __restrict__ wk,
                                             const float* __restrict__ wv,
                                             const float* __restrict__ wp,
                                             bf16* __restrict__ dst) {
    int i = blockIdx.x * 256 + threadIdx.x;
    dst[i] = (bf16)wq[i];
    dst[65536 + i] = (bf16)wk[i];
    dst[131072 + i] = (bf16)wv[i];
    dst[196608 + i] = (bf16)wp[i];
}

// ---------------------------------------------------------------------------
// Kernel 4: merged Q+K+V NT GEMM, fp8 epilogue.
//   q8/k8: PLAIN token-major fp8 (the 32x32x64 MX fragment uses the same
//          k-slot<->channel map for A and B, so no channel permutation).
//   v8:    megatile layout [b][h][mt(32)][hb(2)][ch(256)][j(32)], where for
//          key k6 = n&63: hb = (k6>>2)&1, j = ((k6>>5)<<4)|(((k6>>3)&3)<<2)|(k6&3),
//          and j's 16B-unit is XOR-swizzled by ((ch^hb)&1) for bank-freedom.
//          This IS the attn LDS layout, so staging is a linear 16KB copy.
// ---------------------------------------------------------------------------
__global__ __launch_bounds__(256) void gemm_qkv(const bf16* __restrict__ A,
                                                const bf16* __restrict__ Wq,
                                                const bf16* __restrict__ Wk,
                                                const bf16* __restrict__ Wv,
                                                const float* __restrict__ bq,
                                                const float* __restrict__ bk,
                                                const float* __restrict__ bv,
                                                u8* __restrict__ q8,
                                                u8* __restrict__ k8,
                                                u8* __restrict__ v8) {
    __shared__ __align__(16) bf16 As[64][32];
    __shared__ __align__(16) bf16 Wqs[64][32];
    __shared__ __align__(16) bf16 Wks[64][32];
    __shared__ __align__(16) bf16 Wvs[64][32];
    int m0 = blockIdx.x * 64;  // token
    int n0 = blockIdx.y * 64;  // out channel
    int tid = threadIdx.x;
    int wv_ = tid >> 6, lane = tid & 63, lr = lane & 15, lq = lane >> 4;
    int wm = (wv_ & 1) * 32, wn = (wv_ >> 1) * 32;
    int sr = tid >> 2, sk = (tid & 3) * 8;  // LDS byte offset == tid*16 (linear)
    f32x4 qacc[2][2] = {}, kacc[2][2] = {}, vacc[2][2] = {};
    for (int kk = 0; kk < C_; kk += 32) {
        __syncthreads();
        gl2lds16(&A[(size_t)(m0 + sr) * C_ + kk + sk], &As[sr][sk]);
        gl2lds16(&Wq[(size_t)(n0 + sr) * C_ + kk + sk], &Wqs[sr][sk]);
        gl2lds16(&Wk[(size_t)(n0 + sr) * C_ + kk + sk], &Wks[sr][sk]);
        gl2lds16(&Wv[(size_t)(n0 + sr) * C_ + kk + sk], &Wvs[sr][sk]);
        __syncthreads();
        bf16x8 a0 = *(const bf16x8*)&As[wm + lr][lq * 8];
        bf16x8 a1 = *(const bf16x8*)&As[wm + 16 + lr][lq * 8];
        bf16x8 q0 = *(const bf16x8*)&Wqs[wn + lr][lq * 8];
        bf16x8 q1 = *(const bf16x8*)&Wqs[wn + 16 + lr][lq * 8];
        bf16x8 k0 = *(const bf16x8*)&Wks[wn + lr][lq * 8];
        bf16x8 k1 = *(const bf16x8*)&Wks[wn + 16 + lr][lq * 8];
        bf16x8 v0 = *(const bf16x8*)&Wvs[wn + lr][lq * 8];
        bf16x8 v1 = *(const bf16x8*)&Wvs[wn + 16 + lr][lq * 8];
        qacc[0][0] = mfma16(a0, q0, qacc[0][0]);
        qacc[0][1] = mfma16(a0, q1, qacc[0][1]);
        qacc[1][0] = mfma16(a1, q0, qacc[1][0]);
        qacc[1][1] = mfma16(a1, q1, qacc[1][1]);
        kacc[0][0] = mfma16(a0, k0, kacc[0][0]);
        kacc[0][1] = mfma16(a0, k1, kacc[0][1]);
        kacc[1][0] = mfma16(a1, k0, kacc[1][0]);
        kacc[1][1] = mfma16(a1, k1, kacc[1][1]);
        vacc[0][0] = mfma16(a0, v0, vacc[0][0]);
        vacc[0][1] = mfma16(a0, v1, vacc[0][1]);
        vacc[1][0] = mfma16(a1, v0, vacc[1][0]);
        vacc[1][1] = mfma16(a1, v1, vacc[1][1]);
    }
    for (int i = 0; i < 2; i++)
        for (int j = 0; j < 2; j++) {
            int col = n0 + wn + j * 16 + lr;
            float bvq = bq[col], bvk = bk[col], bvv = bv[col];
            for (int r = 0; r < 4; r++) {
                int row = m0 + wm + i * 16 + lq * 4 + r;
                q8[(size_t)row * C_ + col] = (u8)f32_to_fp8(qacc[i][j][r] + bvq);
                k8[(size_t)row * C_ + col] = (u8)f32_to_fp8(kacc[i][j][r] + bvk);
                int bb = row >> 12, n = row & (N_ - 1);
                int h = (n >> 11) & 1, mtl = (n >> 6) & 31, k6 = n & 63;
                int hbv = (k6 >> 2) & 1;
                int jv = ((k6 >> 5) << 4) | (((k6 >> 3) & 3) << 2) | (k6 & 3);
                jv ^= ((col ^ hbv) & 1) << 4;
                v8[((size_t)(((bb * 2 + h) * 32 + mtl) * 2 + hbv)) * 8192 +
                   col * 32 + jv] = (u8)f32_to_fp8(vacc[i][j][r] + bvv);
            }
        }
}

// ---------------------------------------------------------------------------
// Kernel 6: fp8 flash attention on MX-scaled 32x32x64 MFMAs (2x fp8 rate),
//   fixed-max softmax, block-level split-K. Wave = 32 queries; megatile =
//   64 keys; per megatile: 8 MX QK^T + 8 MX PV (vs 128 fp8 16x16x32 before).
//   S^T = mfma(K, Q): lane (hb=l>>5, lc=l&31) holds query lc, keys
//   {H*32 + t*8 + hb*4 + m}; P packs sequentially into A-frag bytes, with the
//   matching key permutation baked into v8's layout. K: 3 rotating 8KB LDS
//   buffers; V: single 16KB buffer restaged after PV behind a raw barrier.
//   Counted s_waitcnt vmcnt(4): staged loads stay in flight across barriers.
// ---------------------------------------------------------------------------
__global__ __launch_bounds__(128, 2) void attn(const u8* __restrict__ q,
                                               const u8* __restrict__ k,
                                               const u8* __restrict__ vT,
                                               bf16* __restrict__ O0,
                                               bf16* __restrict__ O1,
                                               float* __restrict__ lp) {
    __shared__ __align__(16) u8 smem[40960];  // K: 3x8192 @0, V: 16384 @24576

    // Bijective XCD swizzle (1024 blocks % 8 == 0): XCD x gets one batch.
    int flat = blockIdx.x + (blockIdx.y << 6) + (blockIdx.z << 7);
    int nid = (flat & 7) * 128 + (flat >> 3);
    int q0 = (nid & 63) * 64;
    int h = (nid >> 6) & 1;
    int b = nid >> 7;
    int tid = threadIdx.x;
    int w = tid >> 6, lane = tid & 63, lc = lane & 31, hb = lane >> 5;

    const u8* kglob = k + ((size_t)(b * N_) + h * 2048) * 256;
    const u8* vglob = vT + ((size_t)(b * 2 + h)) * 32 * 16384;

    // K staging offsets: 16B unit u of row r stored at u ^ (r & 15).
    u32 offK[4];
#pragma unroll
    for (int j = 0; j < 4; j++) {
        int p = j * 128 + tid;  // 0..511
        offK[j] = (u32)((p >> 4) * 256 + (((p & 15) ^ ((p >> 4) & 15)) << 4));
    }

    // Q fragments: lane (hb, lc) holds Q[q0+w*32+lc][kh*64 + hb*32 + 0..31].
    const u8* qrow = q + ((size_t)(b * N_ + q0 + w * 32 + lc)) * 256 + hb * 32;
    i32x8 qf[4];
#pragma unroll
    for (int kh = 0; kh < 4; kh++) qf[kh] = *(const i32x8a*)&qrow[kh * 64];

    f32x16 oacc[8] = {};
    float li = 0.f;
    u32 swz = (u32)(lc & 15);
    u32 vsw0 = (u32)(((lc ^ hb) & 1) << 4);

    auto STAGE_K = [&](int sidx, int buf) {
        const u8* kg = kglob + (size_t)sidx * 8192;
        u8* dst = smem + buf * 8192;
#pragma unroll
        for (int j = 0; j < 4; j++)
            gl2lds16(kg + offK[j], dst + (j * 128 + tid) * 16);
    };
    auto STAGE_V = [&](int t) {
        const u8* vg = vglob + (size_t)t * 16384;
#pragma unroll
        for (int j = 0; j < 8; j++)
            gl2lds16(vg + (j * 128 + tid) * 16, smem + 24576 + (j * 128 + tid) * 16);
    };

    // Prologue: K subtiles 0,1 and V megatile 0 (16 loads in flight).
    STAGE_K(0, 0);
    STAGE_K(1, 1);
    STAGE_V(0);

    for (int mt = 0; mt < 32; mt++) {
        int bufa = (2 * mt) % 3, bufb = (2 * mt + 1) % 3, bufc = (2 * mt + 2) % 3;
        if (mt < 31) {
            STAGE_K(2 * mt + 2, bufc);
            asm volatile("s_waitcnt vmcnt(4)" ::: "memory");
        } else {
            asm volatile("s_waitcnt vmcnt(0)" ::: "memory");
        }
        __builtin_amdgcn_s_barrier();

        const u8* Ka = smem + bufa * 8192;
        const u8* Kb = smem + bufb * 8192;
        __builtin_amdgcn_s_setprio(1);

        // --- S^T = K Q^T: two 32-key halves, K-dim 256 = 4 MX each ---
        f32x16 st0 = {}, st1 = {};
#pragma unroll
        for (int kh = 0; kh < 4; kh++) {
            u32 g0 = (u32)(kh * 4 + hb * 2);
            union { i64x2 h2[2]; i32x8 v; } kf0, kf1;
            kf0.h2[0] = *(const i64x2a*)&Ka[lc * 256 + ((g0 ^ swz) << 4)];
            kf0.h2[1] = *(const i64x2a*)&Ka[lc * 256 + (((g0 + 1) ^ swz) << 4)];
            st0 = mfma_mx(kf0.v, qf[kh], st0);
            kf1.h2[0] = *(const i64x2a*)&Kb[lc * 256 + ((g0 ^ swz) << 4)];
            kf1.h2[1] = *(const i64x2a*)&Kb[lc * 256 + (((g0 + 1) ^ swz) << 4)];
            st1 = mfma_mx(kf1.v, qf[kh], st1);
        }

        // --- fixed-max softmax -> fp8 P, packed in-register (sequential regs) ---
        i32x8 pf;
#pragma unroll
        for (int t4 = 0; t4 < 4; t4++) {
            float a0 = __expf(st0[t4 * 4 + 0] * 0.0625f);
            float a1 = __expf(st0[t4 * 4 + 1] * 0.0625f);
            float a2 = __expf(st0[t4 * 4 + 2] * 0.0625f);
            float a3 = __expf(st0[t4 * 4 + 3] * 0.0625f);
            float b0 = __expf(st1[t4 * 4 + 0] * 0.0625f);
            float b1 = __expf(st1[t4 * 4 + 1] * 0.0625f);
            float b2 = __expf(st1[t4 * 4 + 2] * 0.0625f);
            float b3 = __expf(st1[t4 * 4 + 3] * 0.0625f);
            li += ((a0 + a1) + (a2 + a3)) + ((b0 + b1) + (b2 + b3));
            pf[t4] = (int)((fp8_fast(a0) & 0xff) | ((fp8_fast(a1) & 0xff) << 8) |
                           ((fp8_fast(a2) & 0xff) << 16) | (fp8_fast(a3) << 24));
            pf[4 + t4] = (int)((fp8_fast(b0) & 0xff) | ((fp8_fast(b1) & 0xff) << 8) |
                               ((fp8_fast(b2) & 0xff) << 16) | (fp8_fast(b3) << 24));
        }

        // --- PV: O[32q x 256ch] += P[32x64] V[64x256], 8 MX instrs ---
        const u8* Vb = smem + 24576;
#pragma unroll
        for (int ct = 0; ct < 8; ct++) {
            u32 base = (u32)(hb * 8192 + (ct * 32 + lc) * 32);
            union { i64x2 h2[2]; i32x8 v; } vf;
            vf.h2[0] = *(const i64x2a*)&Vb[base + vsw0];
            vf.h2[1] = *(const i64x2a*)&Vb[base + (vsw0 ^ 16)];
            oacc[ct] = mfma_mx(pf, vf.v, oacc[ct]);
        }
        __builtin_amdgcn_s_setprio(0);

        if (mt < 31) {
            asm volatile("s_waitcnt lgkmcnt(0)" ::: "memory");
            __builtin_amdgcn_s_barrier();  // all waves done reading V(t)/K[2t]
            STAGE_K(2 * mt + 3, bufa);     // overwrites K[2t]'s buffer
            STAGE_V(mt + 1);               // overwrites V(t); lands during QKT(t+1)
        }
    }

    // li: per-lane partial for query lc over keys == [4hb,4hb+4) mod 8.
    float lsum = li + __shfl_xor(li, 32);

    bf16* Op = h ? O1 : O0;
#pragma unroll
    for (int ct = 0; ct < 8; ct++)
#pragma unroll
        for (int r = 0; r < 16; r++) {
            int qq = (r & 3) + hb * 4 + (r >> 2) * 8;
            Op[((size_t)(b * N_ + q0 + w * 32 + qq)) * C_ + ct * 32 + lc] =
                (bf16)oacc[ct][r];
        }
    if (hb == 0)
        lp[((size_t)(h * B_ + b)) * N_ + q0 + w * 32 + lc] = lsum;
}

// ---------------------------------------------------------------------------
// Kernel 7: proj + residual, split-K combine fused into A-staging.
// ---------------------------------------------------------------------------
__global__ __launch_bounds__(256) void proj_res(const bf16* __restrict__ W,
                                                const bf16* __restrict__ O0,
                                                const bf16* __restrict__ O1,
                                                const float* __restrict__ lp,
                                                const float* __restrict__ bias,
                                                const float* __restrict__ x,
                                                float* __restrict__ out) {
    __shared__ __align__(16) bf16 Ws[64][32];
    __shared__ __align__(16) bf16 As[64][32];
    int m0 = blockIdx.x * 64;  // o
    int n0 = blockIdx.y * 64;  // token
    int tid = threadIdx.x;
    int wv_ = tid >> 6, lane = tid & 63, lr = lane & 15, lq = lane >> 4;
    int wm = (wv_ & 1) * 32, wn = (wv_ >> 1) * 32;
    int sr = tid >> 2, sk = (tid & 3) * 8;
    int T = n0 + sr, bb = T >> 12, nn = T & (N_ - 1);
    float inv = 1.f / (lp[(size_t)bb * N_ + nn] + lp[(size_t)(B_ + bb) * N_ + nn]);
    f32x4 acc[2][2] = {};
    for (int kk = 0; kk < C_; kk += 32) {
        __syncthreads();
        gl2lds16(&W[(size_t)(m0 + sr) * C_ + kk + sk], &Ws[sr][sk]);
        bf16x8 o0 = *(const bf16x8*)&O0[(size_t)T * C_ + kk + sk];
        bf16x8 o1 = *(const bf16x8*)&O1[(size_t)T * C_ + kk + sk];
        bf16x8 cm;
#pragma unroll
        for (int e = 0; e < 8; e++) cm[e] = (bf16)(((float)o0[e] + (float)o1[e]) * inv);
        *(bf16x8*)&As[sr][sk] = cm;
        __syncthreads();
        bf16x8 a0 = *(const bf16x8*)&Ws[wm + lr][lq * 8];
        bf16x8 a1 = *(const bf16x8*)&Ws[wm + 16 + lr][lq * 8];
        bf16x8 b0 = *(const bf16x8*)&As[wn + lr][lq * 8];
        bf16x8 b1 = *(const bf16x8*)&As[wn + 16 + lr][lq * 8];
        acc[0][0] = mfma16(a0, b0, acc[0][0]);
        acc[0][1] = mfma16(a0, b1, acc[0][1]);
        acc[1][0] = mfma16(a1, b0, acc[1][0]);
        acc[1][1] = mfma16(a1, b1, acc[1][1]);
    }
    for (int i = 0; i < 2; i++)
        for (int j = 0; j < 2; j++) {
            int Tt = n0 + wn + j * 16 + lr;
            int b = Tt >> 12, n = Tt & (N_ - 1);
            for (int r = 0; r < 4; r++) {
                int o = m0 + wm + i * 16 + lq * 4 + r;
                size_t idx = ((size_t)(b * C_ + o)) * N_ + n;
                out[idx] = x[idx] + acc[i][j][r] + bias[o];
            }
        }
}

// ---------------------------------------------------------------------------
extern "C" void kernel_launch(void* const* d_in, const int* in_sizes, int n_in,
                              void* d_out, int out_size, void* d_ws, size_t ws_size,
                              hipStream_t stream) {
    const float* x = (const float*)d_in[0];
    const float* gsc = (const float*)d_in[1];
    const float* gbi = (const float*)d_in[2];
    const float* wq = (const float*)d_in[3];
    const float* bq = (const float*)d_in[4];
    const float* wk = (const float*)d_in[5];
    const float* bk = (const float*)d_in[6];
    const float* wv = (const float*)d_in[7];
    const float* bv = (const float*)d_in[8];
    const float* wp = (const float*)d_in[9];
    const float* bp = (const float*)d_in[10];
    float* out = (float*)d_out;

    const size_t SZ = (size_t)B_ * N_ * C_;  // 8388608 elements
    char* ws = (char*)d_ws;
    float* gstats = (float*)ws;              // 4 KB slot
    bf16* wb = (bf16*)(ws + 4096);           // 512 KB
    char* base = ws + 4096 + 524288;
    // Layout (59.5 MB total):
    //   [0,      SZ*2) hn  (bf16)  -> reused as O0 after gemm_qkv
    //   [SZ*2,   SZ*3) q8  (fp8, token-major)
    //   [SZ*3,   SZ*4) k8  (fp8, token-major)
    //   [SZ*4,   SZ*5) v8  (fp8, megatiled [b][h][32][16KB])
    //   [SZ*5,   SZ*7) O1  (bf16)
    //   [SZ*7,  +256K) lpart (f32)
    bf16* hn = (bf16*)base;
    u8* q8 = (u8*)(base + SZ * 2);
    u8* k8 = (u8*)(base + SZ * 3);
    u8* v8 = (u8*)(base + SZ * 4);
    bf16* O0 = (bf16*)base;                  // hn dead after gemm_qkv
    bf16* O1 = (bf16*)(base + SZ * 5);
    float* lpart = (float*)(base + SZ * 7);

    cvt_w<<<256, 256, 0, stream>>>(wq, wk, wv, wp, wb);
    gn_stats<<<B_ * G_, 256, 0, stream>>>(x, gstats);
    gn_apply<<<dim3(N_ / 32, C_ / 32, B_), 256, 0, stream>>>(x, gsc, gbi, gstats, hn);
    gemm_qkv<<<dim3(B_ * N_ / 64, C_ / 64), 256, 0, stream>>>(
        hn, wb, wb + 65536, wb + 131072, bq, bk, bv, q8, k8, v8);
    attn<<<dim3(N_ / 64, 2, B_), 128, 0, stream>>>(q8, k8, v8, O0, O1, lpart);
    proj_res<<<dim3(C_ / 64, B_ * N_ / 64), 256, 0, stream>>>(
        wb + 196608, O0, O1, lpart, bp, x, out);
}

// Round 6
// 255.365 us; speedup vs baseline: 1.2685x; 1.0889x over previous
//
#include <hip/hip_runtime.h>

#define B_ 8
#define C_ 256
#define N_ 4096
#define G_ 32

typedef __bf16 bf16;
typedef __bf16 bf16x8 __attribute__((ext_vector_type(8)));
typedef float f32x4 __attribute__((ext_vector_type(4)));
typedef float f32x16 __attribute__((ext_vector_type(16)));
typedef long i64;
typedef long i64x2 __attribute__((ext_vector_type(2)));
typedef long i64x2a __attribute__((ext_vector_type(2), may_alias));
typedef int i32x8 __attribute__((ext_vector_type(8)));
typedef int i32x8a __attribute__((ext_vector_type(8), may_alias));
typedef unsigned int u32;
typedef unsigned char u8;
typedef unsigned short u16;
typedef unsigned long long u64;

__device__ __forceinline__ f32x4 mfma16(bf16x8 a, bf16x8 b, f32x4 c) {
    return __builtin_amdgcn_mfma_f32_16x16x32_bf16(a, b, c, 0, 0, 0);
}
// MX-scaled fp8 MFMA, 32x32x64, unit scales (E8M0 127 = 1.0 in every byte).
__device__ __forceinline__ f32x16 mfma_mx(i32x8 a, i32x8 b, f32x16 c) {
    return __builtin_amdgcn_mfma_scale_f32_32x32x64_f8f6f4(
        a, b, c, 0 /*A=fp8*/, 0 /*B=fp8*/, 0, 0x7F7F7F7F, 0, 0x7F7F7F7F);
}

typedef __attribute__((address_space(1))) const void* gas_t;
typedef __attribute__((address_space(3))) void* las_t;
__device__ __forceinline__ void gl2lds16(const void* g, void* l) {
    __builtin_amdgcn_global_load_lds((gas_t)g, (las_t)l, 16, 0, 0);
}

// Raw v_exp_f32: computes 2^x. (HIP has no __exp2f; exp2f via ocml is fine
// too, but the builtin is the unambiguous 1-instruction spelling.)
__device__ __forceinline__ float exp2_hw(float x) {
    return __builtin_amdgcn_exp2f(x);
}

// Full-range f32 -> OCP e4m3fn (NaN-free by construction).
__device__ __forceinline__ u32 f32_to_fp8(float x) {
    union { float f; u32 u; } c;
    c.f = x;
    u32 s = (c.u >> 24) & 0x80;
    u32 m = (c.u & 0x7fffffff) + 0x00080000;
    int e = (int)(m >> 23) - 127;
    if (e < -6) return s;
    if (e > 8) return s | 0x7e;
    u32 v = ((u32)(e + 7) << 3) | ((m >> 20) & 7);
    if (v > 0x7e) v = 0x7e;
    return s | v;
}
// 3-op converter for known-positive x in [2^-6, 2^8): exp() outputs only.
__device__ __forceinline__ u32 fp8_fast(float x) {
    union { float f; u32 u; } c;
    c.f = x;
    return ((c.u + 0x00080000u) >> 20) - 960u;
}
// Pack 4 f32 -> 4 fp8 bytes. HW packed convert where available (1 instr / 2
// values, RNE, saturating, OCP on gfx950); masked fp8_fast fallback otherwise.
__device__ __forceinline__ u32 pk_fp8x4(float a, float b, float c, float d) {
#if __has_builtin(__builtin_amdgcn_cvt_pk_fp8_f32)
    int w = __builtin_amdgcn_cvt_pk_fp8_f32(a, b, 0, false);
    w = __builtin_amdgcn_cvt_pk_fp8_f32(c, d, w, true);
    return (u32)w;
#else
    return (fp8_fast(a) & 0xff) | ((fp8_fast(b) & 0xff) << 8) |
           ((fp8_fast(c) & 0xff) << 16) | (fp8_fast(d) << 24);
#endif
}

// ---------------------------------------------------------------------------
// Kernel 1: GroupNorm partial sums. 2048 blocks (8 per (batch,group)) so the
// 134 MB read has enough TLP to reach HBM BW (old 256-block grid = 1/CU).
// ---------------------------------------------------------------------------
__global__ __launch_bounds__(256) void gn_part(const float* __restrict__ x,
                                               float* __restrict__ gpart) {
    int blk = blockIdx.x;  // b*256 + g*8 + eighth
    int b = blk >> 8, g = (blk >> 3) & 31, qe = blk & 7;
    int tid = threadIdx.x;
    int c = g * 8 + (tid >> 5);
    const float* row = x + ((size_t)(b * C_ + c)) * N_ + qe * 512;
    float s = 0.f, s2 = 0.f;
    for (int n = (tid & 31) * 4; n < 512; n += 128) {
        float4 v = *(const float4*)(row + n);
        s += v.x + v.y + v.z + v.w;
        s2 += v.x * v.x + v.y * v.y + v.z * v.z + v.w * v.w;
    }
    for (int off = 32; off; off >>= 1) {
        s += __shfl_xor(s, off);
        s2 += __shfl_xor(s2, off);
    }
    __shared__ float red[8];
    int wid = tid >> 6;
    if ((tid & 63) == 0) { red[wid] = s; red[4 + wid] = s2; }
    __syncthreads();
    if (tid == 0) {
        gpart[blk * 2] = red[0] + red[1] + red[2] + red[3];
        gpart[blk * 2 + 1] = red[4] + red[5] + red[6] + red[7];
    }
}

// ---------------------------------------------------------------------------
// Kernel 2: apply GroupNorm + transpose [b][c][n] fp32 -> [b*n][c] bf16.
// Reduces the 8 per-group partials inline (L1-resident, negligible).
// ---------------------------------------------------------------------------
__global__ __launch_bounds__(256) void gn_apply(const float* __restrict__ x,
                                                const float* __restrict__ gsc,
                                                const float* __restrict__ gbi,
                                                const float* __restrict__ gpart,
                                                bf16* __restrict__ hn) {
    __shared__ float tile[32][33];
    int b = blockIdx.z, c0 = blockIdx.y * 32, n0 = blockIdx.x * 32;
    int tx = threadIdx.x & 31, ty = threadIdx.x >> 5;
    for (int i = 0; i < 4; i++) {
        int cl = ty + i * 8;
        int c = c0 + cl;
        int g = c >> 3;
        const float* gp = gpart + ((size_t)(b * G_ + g)) * 16;
        float S = 0.f, S2 = 0.f;
#pragma unroll
        for (int j = 0; j < 8; j++) { S += gp[j * 2]; S2 += gp[j * 2 + 1]; }
        float mean = S * (1.f / 32768.f);
        float var = S2 * (1.f / 32768.f) - mean * mean;
        float rstd = rsqrtf(var + 1e-6f);
        float sc = gsc[c] * rstd;
        float bs = gbi[c] - mean * sc;
        float v = x[((size_t)(b * C_ + c)) * N_ + n0 + tx];
        tile[cl][tx] = v * sc + bs;
    }
    __syncthreads();
    for (int i = 0; i < 4; i++) {
        int nl = ty + i * 8;
        hn[((size_t)(b * N_ + n0 + nl)) * C_ + c0 + tx] = (bf16)tile[tx][nl];
    }
}

// ---------------------------------------------------------------------------
// Kernel 3: convert the four 256x256 fp32 weight matrices to bf16 once.
// ---------------------------------------------------------------------------
__global__ __launch_bounds__(256) void cvt_w(const float* __restrict__ wq,
                                             const float* __restrict__ wk,
                                             const float* __restrict__ wv,
                                             const float* __restrict__ wp,
                                             bf16* __restrict__ dst) {
    int i = blockIdx.x * 256 + threadIdx.x;
    dst[i] = (bf16)wq[i];
    dst[65536 + i] = (bf16)wk[i];
    dst[131072 + i] = (bf16)wv[i];
    dst[196608 + i] = (bf16)wp[i];
}

// ---------------------------------------------------------------------------
// Kernel 4: merged Q+K+V NT GEMM, fp8 epilogue (unchanged from R4).
// ---------------------------------------------------------------------------
__global__ __launch_bounds__(256) void gemm_qkv(const bf16* __restrict__ A,
                                                const bf16* __restrict__ Wq,
                                                const bf16* __restrict__ Wk,
                                                const bf16* __restrict__ Wv,
                                                const float* __restrict__ bq,
                                                const float* __restrict__ bk,
                                                const float* __restrict__ bv,
                                                u8* __restrict__ q8,
                                                u8* __restrict__ k8,
                                                u8* __restrict__ v8) {
    __shared__ __align__(16) bf16 As[64][32];
    __shared__ __align__(16) bf16 Wqs[64][32];
    __shared__ __align__(16) bf16 Wks[64][32];
    __shared__ __align__(16) bf16 Wvs[64][32];
    int m0 = blockIdx.x * 64;  // token
    int n0 = blockIdx.y * 64;  // out channel
    int tid = threadIdx.x;
    int wv_ = tid >> 6, lane = tid & 63, lr = lane & 15, lq = lane >> 4;
    int wm = (wv_ & 1) * 32, wn = (wv_ >> 1) * 32;
    int sr = tid >> 2, sk = (tid & 3) * 8;
    f32x4 qacc[2][2] = {}, kacc[2][2] = {}, vacc[2][2] = {};
    for (int kk = 0; kk < C_; kk += 32) {
        __syncthreads();
        gl2lds16(&A[(size_t)(m0 + sr) * C_ + kk + sk], &As[sr][sk]);
        gl2lds16(&Wq[(size_t)(n0 + sr) * C_ + kk + sk], &Wqs[sr][sk]);
        gl2lds16(&Wk[(size_t)(n0 + sr) * C_ + kk + sk], &Wks[sr][sk]);
        gl2lds16(&Wv[(size_t)(n0 + sr) * C_ + kk + sk], &Wvs[sr][sk]);
        __syncthreads();
        bf16x8 a0 = *(const bf16x8*)&As[wm + lr][lq * 8];
        bf16x8 a1 = *(const bf16x8*)&As[wm + 16 + lr][lq * 8];
        bf16x8 q0 = *(const bf16x8*)&Wqs[wn + lr][lq * 8];
        bf16x8 q1 = *(const bf16x8*)&Wqs[wn + 16 + lr][lq * 8];
        bf16x8 k0 = *(const bf16x8*)&Wks[wn + lr][lq * 8];
        bf16x8 k1 = *(const bf16x8*)&Wks[wn + 16 + lr][lq * 8];
        bf16x8 v0 = *(const bf16x8*)&Wvs[wn + lr][lq * 8];
        bf16x8 v1 = *(const bf16x8*)&Wvs[wn + 16 + lr][lq * 8];
        qacc[0][0] = mfma16(a0, q0, qacc[0][0]);
        qacc[0][1] = mfma16(a0, q1, qacc[0][1]);
        qacc[1][0] = mfma16(a1, q0, qacc[1][0]);
        qacc[1][1] = mfma16(a1, q1, qacc[1][1]);
        kacc[0][0] = mfma16(a0, k0, kacc[0][0]);
        kacc[0][1] = mfma16(a0, k1, kacc[0][1]);
        kacc[1][0] = mfma16(a1, k0, kacc[1][0]);
        kacc[1][1] = mfma16(a1, k1, kacc[1][1]);
        vacc[0][0] = mfma16(a0, v0, vacc[0][0]);
        vacc[0][1] = mfma16(a0, v1, vacc[0][1]);
        vacc[1][0] = mfma16(a1, v0, vacc[1][0]);
        vacc[1][1] = mfma16(a1, v1, vacc[1][1]);
    }
    for (int i = 0; i < 2; i++)
        for (int j = 0; j < 2; j++) {
            int col = n0 + wn + j * 16 + lr;
            float bvq = bq[col], bvk = bk[col], bvv = bv[col];
            for (int r = 0; r < 4; r++) {
                int row = m0 + wm + i * 16 + lq * 4 + r;
                q8[(size_t)row * C_ + col] = (u8)f32_to_fp8(qacc[i][j][r] + bvq);
                k8[(size_t)row * C_ + col] = (u8)f32_to_fp8(kacc[i][j][r] + bvk);
                int bb = row >> 12, n = row & (N_ - 1);
                int h = (n >> 11) & 1, mtl = (n >> 6) & 31, k6 = n & 63;
                int hbv = (k6 >> 2) & 1;
                int jv = ((k6 >> 5) << 4) | (((k6 >> 3) & 3) << 2) | (k6 & 3);
                jv ^= ((col ^ hbv) & 1) << 4;
                v8[((size_t)(((bb * 2 + h) * 32 + mtl) * 2 + hbv)) * 8192 +
                   col * 32 + jv] = (u8)f32_to_fp8(vacc[i][j][r] + bvv);
            }
        }
}

// ---------------------------------------------------------------------------
// Kernel 6: fp8 flash attention on MX 32x32x64 MFMAs. R5: VALU-diet softmax —
//   fused exp2 scale (1 mul saved/exp), v_cvt_pk_fp8_f32 packing (16 instr vs
//   ~96), vector f32x16 l-accumulator (2 pk-adds vs 32 scalar, horizontal
//   reduce once post-loop). Staging/barrier structure identical to R4.
// ---------------------------------------------------------------------------
__global__ __launch_bounds__(128, 2) void attn(const u8* __restrict__ q,
                                               const u8* __restrict__ k,
                                               const u8* __restrict__ vT,
                                               bf16* __restrict__ O0,
                                               bf16* __restrict__ O1,
                                               float* __restrict__ lp) {
    __shared__ __align__(16) u8 smem[40960];  // K: 3x8192 @0, V: 16384 @24576

    int flat = blockIdx.x + (blockIdx.y << 6) + (blockIdx.z << 7);
    int nid = (flat & 7) * 128 + (flat >> 3);
    int q0 = (nid & 63) * 64;
    int h = (nid >> 6) & 1;
    int b = nid >> 7;
    int tid = threadIdx.x;
    int w = tid >> 6, lane = tid & 63, lc = lane & 31, hb = lane >> 5;

    const u8* kglob = k + ((size_t)(b * N_) + h * 2048) * 256;
    const u8* vglob = vT + ((size_t)(b * 2 + h)) * 32 * 16384;

    u32 offK[4];
#pragma unroll
    for (int j = 0; j < 4; j++) {
        int p = j * 128 + tid;  // 0..511
        offK[j] = (u32)((p >> 4) * 256 + (((p & 15) ^ ((p >> 4) & 15)) << 4));
    }

    const u8* qrow = q + ((size_t)(b * N_ + q0 + w * 32 + lc)) * 256 + hb * 32;
    i32x8 qf[4];
#pragma unroll
    for (int kh = 0; kh < 4; kh++) qf[kh] = *(const i32x8a*)&qrow[kh * 64];

    f32x16 oacc[8] = {};
    f32x16 eacc = {};
    u32 swz = (u32)(lc & 15);
    u32 vsw0 = (u32)(((lc ^ hb) & 1) << 4);

    auto STAGE_K = [&](int sidx, int buf) {
        const u8* kg = kglob + (size_t)sidx * 8192;
        u8* dst = smem + buf * 8192;
#pragma unroll
        for (int j = 0; j < 4; j++)
            gl2lds16(kg + offK[j], dst + (j * 128 + tid) * 16);
    };
    auto STAGE_V = [&](int t) {
        const u8* vg = vglob + (size_t)t * 16384;
#pragma unroll
        for (int j = 0; j < 8; j++)
            gl2lds16(vg + (j * 128 + tid) * 16, smem + 24576 + (j * 128 + tid) * 16);
    };

    STAGE_K(0, 0);
    STAGE_K(1, 1);
    STAGE_V(0);

    for (int mt = 0; mt < 32; mt++) {
        int bufa = (2 * mt) % 3, bufb = (2 * mt + 1) % 3, bufc = (2 * mt + 2) % 3;
        if (mt < 31) {
            STAGE_K(2 * mt + 2, bufc);
            asm volatile("s_waitcnt vmcnt(4)" ::: "memory");
        } else {
            asm volatile("s_waitcnt vmcnt(0)" ::: "memory");
        }
        __builtin_amdgcn_s_barrier();

        const u8* Ka = smem + bufa * 8192;
        const u8* Kb = smem + bufb * 8192;
        __builtin_amdgcn_s_setprio(1);

        // --- S^T = K Q^T: two 32-key halves, K-dim 256 = 4 MX each ---
        f32x16 st0 = {}, st1 = {};
#pragma unroll
        for (int kh = 0; kh < 4; kh++) {
            u32 g0 = (u32)(kh * 4 + hb * 2);
            union { i64x2 h2[2]; i32x8 v; } kf0, kf1;
            kf0.h2[0] = *(const i64x2a*)&Ka[lc * 256 + ((g0 ^ swz) << 4)];
            kf0.h2[1] = *(const i64x2a*)&Ka[lc * 256 + (((g0 + 1) ^ swz) << 4)];
            st0 = mfma_mx(kf0.v, qf[kh], st0);
            kf1.h2[0] = *(const i64x2a*)&Kb[lc * 256 + ((g0 ^ swz) << 4)];
            kf1.h2[1] = *(const i64x2a*)&Kb[lc * 256 + (((g0 + 1) ^ swz) << 4)];
            st1 = mfma_mx(kf1.v, qf[kh], st1);
        }

        // --- fixed-max softmax: e = 2^(S * 0.0625*log2e); vector l-accum;
        //     HW packed f32->fp8 converts ---
        f32x16 e0, e1;
#pragma unroll
        for (int i = 0; i < 16; i++) {
            e0[i] = exp2_hw(st0[i] * (1.44269504089f * 0.0625f));
            e1[i] = exp2_hw(st1[i] * (1.44269504089f * 0.0625f));
        }
        eacc += e0;
        eacc += e1;
        i32x8 pf;
#pragma unroll
        for (int t4 = 0; t4 < 4; t4++) {
            pf[t4] = (int)pk_fp8x4(e0[t4 * 4], e0[t4 * 4 + 1], e0[t4 * 4 + 2],
                                   e0[t4 * 4 + 3]);
            pf[4 + t4] = (int)pk_fp8x4(e1[t4 * 4], e1[t4 * 4 + 1], e1[t4 * 4 + 2],
                                       e1[t4 * 4 + 3]);
        }

        // --- PV: O[32q x 256ch] += P[32x64] V[64x256], 8 MX instrs ---
        const u8* Vb = smem + 24576;
#pragma unroll
        for (int ct = 0; ct < 8; ct++) {
            u32 base = (u32)(hb * 8192 + (ct * 32 + lc) * 32);
            union { i64x2 h2[2]; i32x8 v; } vf;
            vf.h2[0] = *(const i64x2a*)&Vb[base + vsw0];
            vf.h2[1] = *(const i64x2a*)&Vb[base + (vsw0 ^ 16)];
            oacc[ct] = mfma_mx(pf, vf.v, oacc[ct]);
        }
        __builtin_amdgcn_s_setprio(0);

        if (mt < 31) {
            asm volatile("s_waitcnt lgkmcnt(0)" ::: "memory");
            __builtin_amdgcn_s_barrier();
            STAGE_K(2 * mt + 3, bufa);
            STAGE_V(mt + 1);
        }
    }

    // Horizontal l reduction: 16 lane-local adds once, then cross-half.
    float hs = 0.f;
#pragma unroll
    for (int i = 0; i < 16; i++) hs += eacc[i];
    float lsum = hs + __shfl_xor(hs, 32);

    bf16* Op = h ? O1 : O0;
#pragma unroll
    for (int ct = 0; ct < 8; ct++)
#pragma unroll
        for (int r = 0; r < 16; r++) {
            int qq = (r & 3) + hb * 4 + (r >> 2) * 8;
            Op[((size_t)(b * N_ + q0 + w * 32 + qq)) * C_ + ct * 32 + lc] =
                (bf16)oacc[ct][r];
        }
    if (hb == 0)
        lp[((size_t)(h * B_ + b)) * N_ + q0 + w * 32 + lc] = lsum;
}

// ---------------------------------------------------------------------------
// Kernel 7: proj + residual, full-o blocks: one block = 64 tokens x 256 out,
// so O0/O1 are read ONCE (old grid read them 4x = +100 MB HBM). W tile
// (16 KB) restaged per block from L2. Combine fused into A-staging as before.
// ---------------------------------------------------------------------------
__global__ __launch_bounds__(256) void proj_res(const bf16* __restrict__ W,
                                                const bf16* __restrict__ O0,
                                                const bf16* __restrict__ O1,
                                                const float* __restrict__ lp,
                                                const float* __restrict__ bias,
                                                const float* __restrict__ x,
                                                float* __restrict__ out) {
    __shared__ __align__(16) bf16 Ws[256][32];  // 16 KB
    __shared__ __align__(16) bf16 As[64][32];   // 4 KB
    int n0 = blockIdx.x * 64;  // token tile
    int tid = threadIdx.x;
    int wv_ = tid >> 6, lane = tid & 63, lr = lane & 15, lq = lane >> 4;
    int wm = (wv_ & 1) * 32;   // token sub-tile of this wave
    int wn = (wv_ >> 1) * 32;  // o sub-tile (within each 64-o chunk)
    int sr = tid >> 2, sk = (tid & 3) * 8;
    int T = n0 + sr, bb = T >> 12, nn = T & (N_ - 1);
    float inv = 1.f / (lp[(size_t)bb * N_ + nn] + lp[(size_t)(B_ + bb) * N_ + nn]);
    f32x4 acc[4][2][2] = {};
    for (int kk = 0; kk < C_; kk += 32) {
        __syncthreads();
#pragma unroll
        for (int p = 0; p < 4; p++)
            gl2lds16(&W[(size_t)(p * 64 + sr) * C_ + kk + sk], &Ws[p * 64 + sr][sk]);
        bf16x8 o0 = *(const bf16x8*)&O0[(size_t)T * C_ + kk + sk];
        bf16x8 o1 = *(const bf16x8*)&O1[(size_t)T * C_ + kk + sk];
        bf16x8 cm;
#pragma unroll
        for (int e = 0; e < 8; e++) cm[e] = (bf16)(((float)o0[e] + (float)o1[e]) * inv);
        *(bf16x8*)&As[sr][sk] = cm;
        __syncthreads();
        bf16x8 a0 = *(const bf16x8*)&As[wm + lr][lq * 8];
        bf16x8 a1 = *(const bf16x8*)&As[wm + 16 + lr][lq * 8];
#pragma unroll
        for (int ot = 0; ot < 4; ot++) {
            bf16x8 w0 = *(const bf16x8*)&Ws[ot * 64 + wn + lr][lq * 8];
            bf16x8 w1 = *(const bf16x8*)&Ws[ot * 64 + wn + 16 + lr][lq * 8];
            acc[ot][0][0] = mfma16(w0, a0, acc[ot][0][0]);
            acc[ot][0][1] = mfma16(w0, a1, acc[ot][0][1]);
            acc[ot][1][0] = mfma16(w1, a0, acc[ot][1][0]);
            acc[ot][1][1] = mfma16(w1, a1, acc[ot][1][1]);
        }
    }
#pragma unroll
    for (int ot = 0; ot < 4; ot++)
        for (int i = 0; i < 2; i++)
            for (int j = 0; j < 2; j++) {
                int Tt = n0 + wm + j * 16 + lr;
                int b = Tt >> 12, n = Tt & (N_ - 1);
                for (int r = 0; r < 4; r++) {
                    int o = ot * 64 + wn + i * 16 + lq * 4 + r;
                    size_t idx = ((size_t)(b * C_ + o)) * N_ + n;
                    out[idx] = x[idx] + acc[ot][i][j][r] + bias[o];
                }
            }
}

// ---------------------------------------------------------------------------
extern "C" void kernel_launch(void* const* d_in, const int* in_sizes, int n_in,
                              void* d_out, int out_size, void* d_ws, size_t ws_size,
                              hipStream_t stream) {
    const float* x = (const float*)d_in[0];
    const float* gsc = (const float*)d_in[1];
    const float* gbi = (const float*)d_in[2];
    const float* wq = (const float*)d_in[3];
    const float* bq = (const float*)d_in[4];
    const float* wk = (const float*)d_in[5];
    const float* bk = (const float*)d_in[6];
    const float* wv = (const float*)d_in[7];
    const float* bv = (const float*)d_in[8];
    const float* wp = (const float*)d_in[9];
    const float* bp = (const float*)d_in[10];
    float* out = (float*)d_out;

    const size_t SZ = (size_t)B_ * N_ * C_;  // 8388608 elements
    char* ws = (char*)d_ws;
    bf16* wb = (bf16*)(ws + 4096);           // 512 KB
    char* base = ws + 4096 + 524288;
    // Layout (59.5 MB total):
    //   [0,      SZ*2) hn  (bf16)  -> reused as O0 after gemm_qkv
    //   [SZ*2,   SZ*3) q8  (fp8, token-major)
    //   [SZ*3,   SZ*4) k8  (fp8, token-major)
    //   [SZ*4,   SZ*5) v8  (fp8, megatiled [b][h][32][16KB])
    //   [SZ*5,   SZ*7) O1  (bf16)
    //   [SZ*7,  +256K) gpart (16KB, dead after gn_apply) then lpart (f32)
    bf16* hn = (bf16*)base;
    u8* q8 = (u8*)(base + SZ * 2);
    u8* k8 = (u8*)(base + SZ * 3);
    u8* v8 = (u8*)(base + SZ * 4);
    bf16* O0 = (bf16*)base;                  // hn dead after gemm_qkv
    bf16* O1 = (bf16*)(base + SZ * 5);
    float* gpart = (float*)(base + SZ * 7);  // time-shared with lpart
    float* lpart = (float*)(base + SZ * 7);

    cvt_w<<<256, 256, 0, stream>>>(wq, wk, wv, wp, wb);
    gn_part<<<B_ * G_ * 8, 256, 0, stream>>>(x, gpart);
    gn_apply<<<dim3(N_ / 32, C_ / 32, B_), 256, 0, stream>>>(x, gsc, gbi, gpart, hn);
    gemm_qkv<<<dim3(B_ * N_ / 64, C_ / 64), 256, 0, stream>>>(
        hn, wb, wb + 65536, wb + 131072, bq, bk, bv, q8, k8, v8);
    attn<<<dim3(N_ / 64, 2, B_), 128, 0, stream>>>(q8, k8, v8, O0, O1, lpart);
    proj_res<<<B_ * N_ / 64, 256, 0, stream>>>(
        wb + 196608, O0, O1, lpart, bp, x, out);
}